// Round 3
// baseline (338.534 us; speedup 1.0000x reference)
//
#include <hip/hip_runtime.h>
#include <stdint.h>

typedef __attribute__((ext_vector_type(4))) float f32x4;
typedef __attribute__((ext_vector_type(8))) short short8_t;     // 8 bf16 for MFMA operand
typedef __attribute__((ext_vector_type(8))) unsigned short ushort8_t;

__device__ __forceinline__ unsigned short f2bf(float f) {
    unsigned int u = __builtin_bit_cast(unsigned int, f);
    u = (u + 0x7fffu + ((u >> 16) & 1u)) >> 16;   // round-to-nearest-even
    return (unsigned short)u;
}
__device__ __forceinline__ float bf2f(unsigned short h) {
    unsigned int u = ((unsigned int)h) << 16;
    return __builtin_bit_cast(float, u);
}

// ---------------------------------------------------------------- prep weights
__global__ __launch_bounds__(256) void prep_w(
    const float* __restrict__ g_w, const float* __restrict__ W_w,
    const float* __restrict__ W_b, const float* __restrict__ gamma,
    const float* __restrict__ beta, const float* __restrict__ mean,
    const float* __restrict__ var,
    unsigned short* __restrict__ gwb, unsigned short* __restrict__ wwb,
    float* __restrict__ bnA, float* __restrict__ bnB)
{
    int i = blockIdx.x * 256 + threadIdx.x;
    if (i < 256 * 512) { gwb[i] = f2bf(g_w[i]); wwb[i] = f2bf(W_w[i]); }
    if (i < 512) {
        float is = rsqrtf(var[i] + 1e-5f);
        float a = gamma[i] * is;
        bnA[i] = a;
        bnB[i] = (W_b[i] - mean[i]) * a + beta[i];
    }
}

// ------------------------------------------------- Qhl: X^T transpose + hi/lo split
// Qhl[b][q][0:512]=hi, [512:1024]=lo.  grid (4096/32, 512/32, 8), block (32,8)
__global__ void build_q(const float* __restrict__ x, unsigned short* __restrict__ Qhl)
{
    __shared__ float t[32][33];
    int b = blockIdx.z, p0 = blockIdx.x * 32, c0 = blockIdx.y * 32;
    const float* xb = x + (long)b * 512 * 4096;
    int tx = threadIdx.x, ty = threadIdx.y;
    for (int i = 0; i < 4; i++)
        t[ty + i * 8][tx] = xb[(long)(c0 + ty + i * 8) * 4096 + p0 + tx];
    __syncthreads();
    unsigned short* qb = Qhl + (long)b * 4096 * 1024;
    for (int i = 0; i < 4; i++) {
        float v = t[tx][ty + i * 8];
        unsigned short hi = f2bf(v);
        unsigned short lo = f2bf(v - bf2f(hi));
        long row = (long)(p0 + ty + i * 8) * 1024;
        qb[row + c0 + tx]       = hi;
        qb[row + 512 + c0 + tx] = lo;
    }
}

// --------------------------------- Khl: maxpool(x) transpose + hi/lo split
// Khl[b][k'][0:512]=hi, [512:1024]=lo.  grid (1024/32, 512/32, 8), block (32,8)
__global__ void build_k(const float* __restrict__ x, unsigned short* __restrict__ Khl)
{
    __shared__ float t[32][33];
    int b = blockIdx.z, k0 = blockIdx.x * 32, c0 = blockIdx.y * 32;
    const float* xb = x + (long)b * 512 * 4096;
    int tx = threadIdx.x, ty = threadIdx.y;
    for (int i = 0; i < 4; i++) {
        int c = c0 + ty + i * 8;
        int k = k0 + tx;
        int h = k >> 5, w = k & 31;
        const float* base = xb + (long)c * 4096 + h * 128 + w * 2;
        float v = fmaxf(fmaxf(base[0], base[1]), fmaxf(base[64], base[65]));
        t[ty + i * 8][tx] = v;
    }
    __syncthreads();
    unsigned short* kb = Khl + (long)b * 1024 * 1024;
    for (int i = 0; i < 4; i++) {
        float v = t[tx][ty + i * 8];
        unsigned short hi = f2bf(v);
        unsigned short lo = f2bf(v - bf2f(hi));
        long row = (long)(k0 + ty + i * 8) * 1024;
        kb[row + c0 + tx]       = hi;
        kb[row + 512 + c0 + tx] = lo;
    }
}

// ---------------- V build: Gp[b][ci][k'] = bf16(g_b[ci] + maxpool2(Gt)[ci][k'])
// Gt is bf16 [b][p=4096][ci=256].  grid (1024/32, 256/8, 8), block 256
__global__ __launch_bounds__(256) void build_v(
    const unsigned short* __restrict__ Gt, const float* __restrict__ g_b,
    unsigned short* __restrict__ Gp)
{
    int b = blockIdx.z;
    int k  = blockIdx.x * 32 + (threadIdx.x & 31);
    int ci = blockIdx.y * 8 + (threadIdx.x >> 5);
    int h = k >> 5, w = k & 31;
    const unsigned short* g = Gt + (long)b * 4096 * 256;
    long p = (long)(h * 128 + w * 2) * 256 + ci;
    float v0 = bf2f(g[p]),        v1 = bf2f(g[p + 256]);
    float v2 = bf2f(g[p + 64*256]), v3 = bf2f(g[p + 65*256]);
    float v = fmaxf(fmaxf(v0, v1), fmaxf(v2, v3)) + g_b[ci];
    Gp[(long)b * 256 * 1024 + (long)ci * 1024 + k] = f2bf(v);
}

// ----------------------- softmax over rows of 1024, in-place P (bf16) at row start
__global__ __launch_bounds__(256) void softmax_rows(float* __restrict__ S)
{
    long row = blockIdx.x;
    float* r = S + row * 1024;
    int tid = threadIdx.x;
    float4 v = ((const float4*)r)[tid];
    float m = fmaxf(fmaxf(v.x, v.y), fmaxf(v.z, v.w));
    for (int off = 32; off; off >>= 1) m = fmaxf(m, __shfl_xor(m, off));
    __shared__ float redm[4], reds[4];
    int wid = tid >> 6, lane = tid & 63;
    if (lane == 0) redm[wid] = m;
    __syncthreads();
    m = fmaxf(fmaxf(redm[0], redm[1]), fmaxf(redm[2], redm[3]));
    float e0 = __expf(v.x - m), e1 = __expf(v.y - m);
    float e2 = __expf(v.z - m), e3 = __expf(v.w - m);
    float s = e0 + e1 + e2 + e3;
    for (int off = 32; off; off >>= 1) s += __shfl_xor(s, off);
    if (lane == 0) reds[wid] = s;
    __syncthreads();
    s = reds[0] + reds[1] + reds[2] + reds[3];
    float inv = 1.0f / s;
    ushort4 p;
    p.x = f2bf(e0 * inv); p.y = f2bf(e1 * inv);
    p.z = f2bf(e2 * inv); p.w = f2bf(e3 * inv);
    ((ushort4*)r)[tid] = p;   // first 2KB of the 4KB row
}

// -------------------------------------------------------------------- GEMM
// C[m][n] = sum_k A[m][k]*B[n][k]  (A row-major along k, B row-major along k)
// 128x128 tile, BK=64, 256 threads = 4 waves in 2x2, each wave 64x64 out.
// AFOLD/BFOLD: virtual-K region fold (k0 >= FOLD -> k0-FOLD) for hi/lo split GEMM.
// EPI: 0 = f32 store, 1 = bf16 store, 2 = v*bnA[m]+bnB[m]+Xres then f32 store.
template<int EPI, int AFOLD, int BFOLD>
__global__ __launch_bounds__(256) void gemm_abt(
    const unsigned short* __restrict__ A, int lda, long abstr,
    const unsigned short* __restrict__ B, int ldb, long bbstr,
    void* __restrict__ Cv, int ldc, long cbstr,
    int K,
    const float* __restrict__ bnA, const float* __restrict__ bnB,
    const float* __restrict__ Xres, long xbstr)
{
    __shared__ unsigned short lA[128 * 64];
    __shared__ unsigned short lB[128 * 64];
    const int tid = threadIdx.x;
    const int wid = tid >> 6, lane = tid & 63;
    const int z = blockIdx.z;
    const int m0 = blockIdx.y * 128, n0 = blockIdx.x * 128;
    const unsigned short* Ab = A + z * abstr;
    const unsigned short* Bb = B + z * bbstr;
    const int wr = wid >> 1, wc = wid & 1;
    const int srow = tid >> 3;          // 0..31
    const int scol = (tid & 7) * 8;     // 0..56
    const int lr = lane & 15, lg = lane >> 4;

    f32x4 acc[4][4];
    for (int mi = 0; mi < 4; mi++)
        for (int ni = 0; ni < 4; ni++)
            acc[mi][ni] = (f32x4){0.f, 0.f, 0.f, 0.f};

    for (int k0 = 0; k0 < K; k0 += 64) {
        int ak0 = (AFOLD && k0 >= AFOLD) ? k0 - AFOLD : k0;
        int bk0 = (BFOLD && k0 >= BFOLD) ? k0 - BFOLD : k0;
        ushort8_t av[4], bv[4];
        for (int i = 0; i < 4; i++) {
            av[i] = *(const ushort8_t*)(Ab + (long)(m0 + srow + i * 32) * lda + ak0 + scol);
            bv[i] = *(const ushort8_t*)(Bb + (long)(n0 + srow + i * 32) * ldb + bk0 + scol);
        }
        __syncthreads();   // previous iter's LDS reads complete
        for (int i = 0; i < 4; i++) {
            int row = srow + i * 32;
            int chs = ((scol >> 3) ^ (row & 7)) * 8;   // XOR chunk swizzle
            *(ushort8_t*)(&lA[row * 64 + chs]) = av[i];
            *(ushort8_t*)(&lB[row * 64 + chs]) = bv[i];
        }
        __syncthreads();
        for (int kk = 0; kk < 2; kk++) {
            short8_t af[4], bf[4];
            for (int mi = 0; mi < 4; mi++) {
                int row = wr * 64 + mi * 16 + lr;
                int ch = ((kk * 4 + lg) ^ (row & 7)) * 8;
                af[mi] = *(const short8_t*)(&lA[row * 64 + ch]);
            }
            for (int ni = 0; ni < 4; ni++) {
                int row = wc * 64 + ni * 16 + lr;
                int ch = ((kk * 4 + lg) ^ (row & 7)) * 8;
                bf[ni] = *(const short8_t*)(&lB[row * 64 + ch]);
            }
            for (int mi = 0; mi < 4; mi++)
                for (int ni = 0; ni < 4; ni++)
                    acc[mi][ni] = __builtin_amdgcn_mfma_f32_16x16x32_bf16(
                        af[mi], bf[ni], acc[mi][ni], 0, 0, 0);
        }
    }

    // epilogue: lane holds D[row=(lane>>4)*4+r][col=lane&15]
    for (int mi = 0; mi < 4; mi++) {
        for (int ni = 0; ni < 4; ni++) {
            int ncol = n0 + wc * 64 + ni * 16 + lr;
            int mrow = m0 + wr * 64 + mi * 16 + lg * 4;
            for (int r = 0; r < 4; r++) {
                int row = mrow + r;
                float v = acc[mi][ni][r];
                long idx = z * cbstr + (long)row * ldc + ncol;
                if (EPI == 0) {
                    ((float*)Cv)[idx] = v;
                } else if (EPI == 1) {
                    ((unsigned short*)Cv)[idx] = f2bf(v);
                } else {
                    float o = v * bnA[row] + bnB[row] + Xres[z * xbstr + (long)row * ldc + ncol];
                    ((float*)Cv)[idx] = o;
                }
            }
        }
    }
}

// fallback if workspace too small (diagnostic: out = x)
__global__ void copy_residual(const float* __restrict__ x, float* __restrict__ out, long n)
{
    for (long i = blockIdx.x * 256ll + threadIdx.x; i < n; i += (long)gridDim.x * 256)
        out[i] = x[i];
}

extern "C" void kernel_launch(void* const* d_in, const int* in_sizes, int n_in,
                              void* d_out, int out_size, void* d_ws, size_t ws_size,
                              hipStream_t stream)
{
    const float* x     = (const float*)d_in[0];
    const float* g_w   = (const float*)d_in[1];
    const float* g_b   = (const float*)d_in[2];
    const float* W_w   = (const float*)d_in[3];
    const float* W_b   = (const float*)d_in[4];
    const float* gamma = (const float*)d_in[5];
    const float* beta  = (const float*)d_in[6];
    const float* mean  = (const float*)d_in[7];
    const float* var   = (const float*)d_in[8];
    float* out = (float*)d_out;

    char* ws = (char*)d_ws;
    size_t o = 0;
    auto alloc = [&](size_t bytes) { size_t r = o; o = (o + bytes + 255) & ~(size_t)255; return r; };
    size_t o_gwb = alloc(256 * 512 * 2);
    size_t o_wwb = alloc(512 * 256 * 2);
    size_t o_bnA = alloc(512 * 4);
    size_t o_bnB = alloc(512 * 4);
    size_t o_q   = alloc(8ull * 4096 * 1024 * 2);  // Qhl (hi|lo)
    size_t o_k   = alloc(8ull * 1024 * 1024 * 2);  // Khl (hi|lo)
    size_t o_gp  = alloc(8ull * 256 * 1024 * 2);   // V^T (pooled g, bf16)
    size_t o_y   = alloc(8ull * 4096 * 256 * 2);   // Y (also holds Gt before pooling)
    size_t o_s   = o;                               // S fp32 (P bf16 in-place)
    const size_t srow_bytes = 1024ull * 4;          // one S row (fp32)
    const size_t sb1 = 4096ull * srow_bytes;        // one batch of S

    // Plan: G = batches of S at once (z-grouped); else RC = row-chunk within a batch.
    int G = 0, RC = 0;
    if      (o_s + 8 * sb1 <= ws_size) G = 8;
    else if (o_s + 4 * sb1 <= ws_size) G = 4;
    else if (o_s + 2 * sb1 <= ws_size) G = 2;
    else if (o_s + 1 * sb1 <= ws_size) G = 1;
    else {
        for (int rc = 2048; rc >= 128; rc >>= 1)
            if (o_s + (size_t)rc * srow_bytes <= ws_size) { RC = rc; break; }
        if (!RC) {  // ws too small — diagnostic fallback
            copy_residual<<<dim3(2048), dim3(256), 0, stream>>>(x, out, (long)out_size);
            return;
        }
    }

    unsigned short* gwb = (unsigned short*)(ws + o_gwb);
    unsigned short* wwb = (unsigned short*)(ws + o_wwb);
    float* bnA = (float*)(ws + o_bnA);
    float* bnB = (float*)(ws + o_bnB);
    unsigned short* Qhl = (unsigned short*)(ws + o_q);
    unsigned short* Khl = (unsigned short*)(ws + o_k);
    unsigned short* Gp  = (unsigned short*)(ws + o_gp);
    unsigned short* Y   = (unsigned short*)(ws + o_y);
    float* S = (float*)(ws + o_s);

    prep_w<<<dim3(512), dim3(256), 0, stream>>>(g_w, W_w, W_b, gamma, beta, mean, var,
                                                gwb, wwb, bnA, bnB);
    build_q<<<dim3(128, 16, 8), dim3(32, 8), 0, stream>>>(x, Qhl);
    build_k<<<dim3(32, 16, 8), dim3(32, 8), 0, stream>>>(x, Khl);

    // G-conv: Gt[b][p][ci] (bf16, into Y slot) = Qhl_hi · gwb^T   (M=4096,N=256,K=512)
    gemm_abt<1, 0, 0><<<dim3(2, 32, 8), dim3(256), 0, stream>>>(
        Qhl, 1024, 4096l * 1024,
        gwb, 512, 0,
        (void*)Y, 256, 4096l * 256, 512,
        nullptr, nullptr, nullptr, 0);

    build_v<<<dim3(32, 32, 8), dim3(256), 0, stream>>>(Y, g_b, Gp);

    if (G) {
        for (int bg = 0; bg < 8; bg += G) {
            // QK^T with hi/lo split via virtual K=1536:
            //  j<512: qh*kh ; 512<=j<1024: qh*kl ; j>=1024: ql*kh
            gemm_abt<0, 512, 1024><<<dim3(8, 32, G), dim3(256), 0, stream>>>(
                Qhl + (size_t)bg * 4096 * 1024, 1024, 4096l * 1024,
                Khl + (size_t)bg * 1024 * 1024, 1024, 1024l * 1024,
                (void*)S, 1024, 4096l * 1024, 1536,
                nullptr, nullptr, nullptr, 0);
            softmax_rows<<<dim3(G * 4096), dim3(256), 0, stream>>>(S);
            // PV: Y[b][q][ci] = P · Gp^T   (M=4096,N=256,K=1024); P bf16 rows inside S
            gemm_abt<1, 0, 0><<<dim3(2, 32, G), dim3(256), 0, stream>>>(
                (const unsigned short*)S, 2048, 4096l * 2048,
                Gp + (size_t)bg * 256 * 1024, 1024, 256l * 1024,
                (void*)(Y + (size_t)bg * 4096 * 256), 256, 4096l * 256, 1024,
                nullptr, nullptr, nullptr, 0);
        }
    } else {
        // Row-chunked path (small workspace): S holds RC rows at a time.
        for (int b = 0; b < 8; b++) {
            for (int r0 = 0; r0 < 4096; r0 += RC) {
                const unsigned short* Aq = Qhl + (size_t)b * 4096 * 1024 + (size_t)r0 * 1024;
                gemm_abt<0, 512, 1024><<<dim3(8, RC / 128, 1), dim3(256), 0, stream>>>(
                    Aq, 1024, 0,
                    Khl + (size_t)b * 1024 * 1024, 1024, 0,
                    (void*)S, 1024, 0, 1536,
                    nullptr, nullptr, nullptr, 0);
                softmax_rows<<<dim3(RC), dim3(256), 0, stream>>>(S);
                gemm_abt<1, 0, 0><<<dim3(2, RC / 128, 1), dim3(256), 0, stream>>>(
                    (const unsigned short*)S, 2048, 0,
                    Gp + (size_t)b * 256 * 1024, 1024, 0,
                    (void*)(Y + ((size_t)b * 4096 + r0) * 256), 256, 0, 1024,
                    nullptr, nullptr, nullptr, 0);
            }
        }
    }

    // W-conv + BN + residual: out[b][o][p] = (wwb·Y^T)*bnA[o]+bnB[o]+x  (M=512,N=4096,K=256)
    gemm_abt<2, 0, 0><<<dim3(32, 4, 8), dim3(256), 0, stream>>>(
        wwb, 256, 0,
        Y, 256, 4096l * 256,
        (void*)out, 4096, 512l * 4096, 256,
        bnA, bnB, x, 512l * 4096);
}

// Round 4
// 326.439 us; speedup vs baseline: 1.0371x; 1.0371x over previous
//
#include <hip/hip_runtime.h>
#include <stdint.h>

typedef __attribute__((ext_vector_type(4))) float f32x4;
typedef __attribute__((ext_vector_type(8))) short short8_t;     // 8 bf16 for MFMA operand
typedef __attribute__((ext_vector_type(8))) unsigned short ushort8_t;

__device__ __forceinline__ unsigned short f2bf(float f) {
    unsigned int u = __builtin_bit_cast(unsigned int, f);
    u = (u + 0x7fffu + ((u >> 16) & 1u)) >> 16;   // round-to-nearest-even
    return (unsigned short)u;
}
__device__ __forceinline__ float bf2f(unsigned short h) {
    unsigned int u = ((unsigned int)h) << 16;
    return __builtin_bit_cast(float, u);
}

// async global->LDS, 16B per lane. LDS dest = wave-uniform base + lane*16.
__device__ __forceinline__ void gll16(const unsigned short* g, unsigned short* l) {
    __builtin_amdgcn_global_load_lds(
        (const __attribute__((address_space(1))) void*)g,
        (__attribute__((address_space(3))) void*)l, 16, 0, 0);
}

// ---------------------------------------------------------------- prep weights
__global__ __launch_bounds__(256) void prep_w(
    const float* __restrict__ g_w, const float* __restrict__ W_w,
    const float* __restrict__ W_b, const float* __restrict__ gamma,
    const float* __restrict__ beta, const float* __restrict__ mean,
    const float* __restrict__ var,
    unsigned short* __restrict__ gwb, unsigned short* __restrict__ wwb,
    float* __restrict__ bnA, float* __restrict__ bnB)
{
    int i = blockIdx.x * 256 + threadIdx.x;
    if (i < 256 * 512) { gwb[i] = f2bf(g_w[i]); wwb[i] = f2bf(W_w[i]); }
    if (i < 512) {
        float is = rsqrtf(var[i] + 1e-5f);
        float a = gamma[i] * is;
        bnA[i] = a;
        bnB[i] = (W_b[i] - mean[i]) * a + beta[i];
    }
}

// ------------------------------------------------- Qhl: X^T transpose + hi/lo split
// Qhl[b][q][0:512]=hi, [512:1024]=lo.  grid (4096/32, 512/32, 8), block (32,8)
__global__ void build_q(const float* __restrict__ x, unsigned short* __restrict__ Qhl)
{
    __shared__ float t[32][33];
    int b = blockIdx.z, p0 = blockIdx.x * 32, c0 = blockIdx.y * 32;
    const float* xb = x + (long)b * 512 * 4096;
    int tx = threadIdx.x, ty = threadIdx.y;
    for (int i = 0; i < 4; i++)
        t[ty + i * 8][tx] = xb[(long)(c0 + ty + i * 8) * 4096 + p0 + tx];
    __syncthreads();
    unsigned short* qb = Qhl + (long)b * 4096 * 1024;
    for (int i = 0; i < 4; i++) {
        float v = t[tx][ty + i * 8];
        unsigned short hi = f2bf(v);
        unsigned short lo = f2bf(v - bf2f(hi));
        long row = (long)(p0 + ty + i * 8) * 1024;
        qb[row + c0 + tx]       = hi;
        qb[row + 512 + c0 + tx] = lo;
    }
}

// --------------------------------- Khl: maxpool(x) transpose + hi/lo split
// Khl[b][k'][0:512]=hi, [512:1024]=lo.  grid (1024/32, 512/32, 8), block (32,8)
__global__ void build_k(const float* __restrict__ x, unsigned short* __restrict__ Khl)
{
    __shared__ float t[32][33];
    int b = blockIdx.z, k0 = blockIdx.x * 32, c0 = blockIdx.y * 32;
    const float* xb = x + (long)b * 512 * 4096;
    int tx = threadIdx.x, ty = threadIdx.y;
    for (int i = 0; i < 4; i++) {
        int c = c0 + ty + i * 8;
        int k = k0 + tx;
        int h = k >> 5, w = k & 31;
        const float* base = xb + (long)c * 4096 + h * 128 + w * 2;
        float v = fmaxf(fmaxf(base[0], base[1]), fmaxf(base[64], base[65]));
        t[ty + i * 8][tx] = v;
    }
    __syncthreads();
    unsigned short* kb = Khl + (long)b * 1024 * 1024;
    for (int i = 0; i < 4; i++) {
        float v = t[tx][ty + i * 8];
        unsigned short hi = f2bf(v);
        unsigned short lo = f2bf(v - bf2f(hi));
        long row = (long)(k0 + ty + i * 8) * 1024;
        kb[row + c0 + tx]       = hi;
        kb[row + 512 + c0 + tx] = lo;
    }
}

// ---------------- V build: Gp[b][ci][k'] = bf16(g_b[ci] + maxpool2(Gt)[ci][k'])
// Gt is bf16 [b][p=4096][ci=256].  grid (1024/32, 256/8, 8), block 256
__global__ __launch_bounds__(256) void build_v(
    const unsigned short* __restrict__ Gt, const float* __restrict__ g_b,
    unsigned short* __restrict__ Gp)
{
    int b = blockIdx.z;
    int k  = blockIdx.x * 32 + (threadIdx.x & 31);
    int ci = blockIdx.y * 8 + (threadIdx.x >> 5);
    int h = k >> 5, w = k & 31;
    const unsigned short* g = Gt + (long)b * 4096 * 256;
    long p = (long)(h * 128 + w * 2) * 256 + ci;
    float v0 = bf2f(g[p]),        v1 = bf2f(g[p + 256]);
    float v2 = bf2f(g[p + 64*256]), v3 = bf2f(g[p + 65*256]);
    float v = fmaxf(fmaxf(v0, v1), fmaxf(v2, v3)) + g_b[ci];
    Gp[(long)b * 256 * 1024 + (long)ci * 1024 + k] = f2bf(v);
}

// ----------------------- softmax over rows of 1024, in-place P (bf16) at row start
__global__ __launch_bounds__(256) void softmax_rows(float* __restrict__ S)
{
    long row = blockIdx.x;
    float* r = S + row * 1024;
    int tid = threadIdx.x;
    float4 v = ((const float4*)r)[tid];
    float m = fmaxf(fmaxf(v.x, v.y), fmaxf(v.z, v.w));
    for (int off = 32; off; off >>= 1) m = fmaxf(m, __shfl_xor(m, off));
    __shared__ float redm[4], reds[4];
    int wid = tid >> 6, lane = tid & 63;
    if (lane == 0) redm[wid] = m;
    __syncthreads();
    m = fmaxf(fmaxf(redm[0], redm[1]), fmaxf(redm[2], redm[3]));
    float e0 = __expf(v.x - m), e1 = __expf(v.y - m);
    float e2 = __expf(v.z - m), e3 = __expf(v.w - m);
    float s = e0 + e1 + e2 + e3;
    for (int off = 32; off; off >>= 1) s += __shfl_xor(s, off);
    if (lane == 0) reds[wid] = s;
    __syncthreads();
    s = reds[0] + reds[1] + reds[2] + reds[3];
    float inv = 1.0f / s;
    ushort4 p;
    p.x = f2bf(e0 * inv); p.y = f2bf(e1 * inv);
    p.z = f2bf(e2 * inv); p.w = f2bf(e3 * inv);
    ((ushort4*)r)[tid] = p;   // first 2KB of the 4KB row
}

// -------------------------------------------------------------------- GEMM
// C[m][n] = sum_k A[m][k]*B[n][k]  (A row-major along k, B row-major along k)
// 128x128 tile, BK=64, 256 threads = 4 waves in 2x2, each wave 64x64 out.
// Staging: global_load_lds dwordx4, linear LDS dest, XOR-swizzled global source;
// read side applies the same XOR (rule #21: both-sides-or-neither).
// Block index is XCD-remapped (T1) when nwg%8==0.
// AFOLD/BFOLD: virtual-K region fold (k0 >= FOLD -> k0-FOLD) for hi/lo split GEMM.
// EPI: 0 = f32 store, 1 = bf16 store, 2 = v*bnA[m]+bnB[m]+Xres then f32 store.
template<int EPI, int AFOLD, int BFOLD>
__global__ __launch_bounds__(256) void gemm_abt(
    const unsigned short* __restrict__ A, int lda, long abstr,
    const unsigned short* __restrict__ B, int ldb, long bbstr,
    void* __restrict__ Cv, int ldc, long cbstr,
    int K,
    const float* __restrict__ bnA, const float* __restrict__ bnB,
    const float* __restrict__ Xres, long xbstr)
{
    __shared__ unsigned short lA[128 * 64];
    __shared__ unsigned short lB[128 * 64];
    const int tid = threadIdx.x;
    const int wid = tid >> 6, lane = tid & 63;

    // ---- XCD-aware block remap (bijective; identity if nwg%8 != 0)
    unsigned gx = gridDim.x, gy = gridDim.y;
    unsigned nwg = gx * gy * gridDim.z;
    unsigned lin = blockIdx.x + gx * (blockIdx.y + gy * blockIdx.z);
    unsigned l = ((nwg & 7u) == 0u) ? ((lin & 7u) * (nwg >> 3) + (lin >> 3)) : lin;
    unsigned bx = l % gx;
    unsigned rem = l / gx;
    unsigned by = rem % gy;
    unsigned bz = rem / gy;

    const int z = (int)bz;
    const int m0 = (int)by * 128, n0 = (int)bx * 128;
    const unsigned short* Ab = A + z * abstr;
    const unsigned short* Bb = B + z * bbstr;
    const int wr = wid >> 1, wc = wid & 1;
    const int lr = lane & 15, lg = lane >> 4;

    // staging geometry: instr i covers 8 rows starting at i*32 + wid*8;
    // lane l -> row (l>>3) in group, source chunk (l&7)^(l>>3) (XOR pre-swizzle)
    const int srA = lane >> 3;                         // 0..7
    const int scg = (((lane & 7) ^ srA) << 3);         // element offset 0..56

    f32x4 acc[4][4];
    for (int mi = 0; mi < 4; mi++)
        for (int ni = 0; ni < 4; ni++)
            acc[mi][ni] = (f32x4){0.f, 0.f, 0.f, 0.f};

    for (int k0 = 0; k0 < K; k0 += 64) {
        int ak0 = (AFOLD && k0 >= AFOLD) ? k0 - AFOLD : k0;
        int bk0 = (BFOLD && k0 >= BFOLD) ? k0 - BFOLD : k0;
        __syncthreads();   // previous iter's LDS reads complete
        for (int i = 0; i < 4; i++) {
            int rowbase = i * 32 + wid * 8;
            gll16(Ab + (long)(m0 + rowbase + srA) * lda + ak0 + scg, &lA[rowbase * 64]);
            gll16(Bb + (long)(n0 + rowbase + srA) * ldb + bk0 + scg, &lB[rowbase * 64]);
        }
        __syncthreads();   // drains vmcnt(0): tiles resident
        for (int kk = 0; kk < 2; kk++) {
            short8_t af[4], bf[4];
            for (int mi = 0; mi < 4; mi++) {
                int row = wr * 64 + mi * 16 + lr;
                int ch = ((kk * 4 + lg) ^ (row & 7)) * 8;
                af[mi] = *(const short8_t*)(&lA[row * 64 + ch]);
            }
            for (int ni = 0; ni < 4; ni++) {
                int row = wc * 64 + ni * 16 + lr;
                int ch = ((kk * 4 + lg) ^ (row & 7)) * 8;
                bf[ni] = *(const short8_t*)(&lB[row * 64 + ch]);
            }
            for (int mi = 0; mi < 4; mi++)
                for (int ni = 0; ni < 4; ni++)
                    acc[mi][ni] = __builtin_amdgcn_mfma_f32_16x16x32_bf16(
                        af[mi], bf[ni], acc[mi][ni], 0, 0, 0);
        }
    }

    // epilogue: lane holds D[row=(lane>>4)*4+r][col=lane&15]
    for (int mi = 0; mi < 4; mi++) {
        for (int ni = 0; ni < 4; ni++) {
            int ncol = n0 + wc * 64 + ni * 16 + lr;
            int mrow = m0 + wr * 64 + mi * 16 + lg * 4;
            for (int r = 0; r < 4; r++) {
                int row = mrow + r;
                float v = acc[mi][ni][r];
                long idx = z * cbstr + (long)row * ldc + ncol;
                if (EPI == 0) {
                    ((float*)Cv)[idx] = v;
                } else if (EPI == 1) {
                    ((unsigned short*)Cv)[idx] = f2bf(v);
                } else {
                    float o = v * bnA[row] + bnB[row] + Xres[z * xbstr + (long)row * ldc + ncol];
                    ((float*)Cv)[idx] = o;
                }
            }
        }
    }
}

// fallback if workspace too small (diagnostic: out = x)
__global__ void copy_residual(const float* __restrict__ x, float* __restrict__ out, long n)
{
    for (long i = blockIdx.x * 256ll + threadIdx.x; i < n; i += (long)gridDim.x * 256)
        out[i] = x[i];
}

extern "C" void kernel_launch(void* const* d_in, const int* in_sizes, int n_in,
                              void* d_out, int out_size, void* d_ws, size_t ws_size,
                              hipStream_t stream)
{
    const float* x     = (const float*)d_in[0];
    const float* g_w   = (const float*)d_in[1];
    const float* g_b   = (const float*)d_in[2];
    const float* W_w   = (const float*)d_in[3];
    const float* W_b   = (const float*)d_in[4];
    const float* gamma = (const float*)d_in[5];
    const float* beta  = (const float*)d_in[6];
    const float* mean  = (const float*)d_in[7];
    const float* var   = (const float*)d_in[8];
    float* out = (float*)d_out;

    char* ws = (char*)d_ws;
    size_t o = 0;
    auto alloc = [&](size_t bytes) { size_t r = o; o = (o + bytes + 255) & ~(size_t)255; return r; };
    size_t o_gwb = alloc(256 * 512 * 2);
    size_t o_wwb = alloc(512 * 256 * 2);
    size_t o_bnA = alloc(512 * 4);
    size_t o_bnB = alloc(512 * 4);
    size_t o_q   = alloc(8ull * 4096 * 1024 * 2);  // Qhl (hi|lo)
    size_t o_k   = alloc(8ull * 1024 * 1024 * 2);  // Khl (hi|lo)
    size_t o_gp  = alloc(8ull * 256 * 1024 * 2);   // V^T (pooled g, bf16)
    size_t o_y   = alloc(8ull * 4096 * 256 * 2);   // Y (also holds Gt before pooling)
    size_t o_s   = o;                               // S fp32 (P bf16 in-place)
    const size_t srow_bytes = 1024ull * 4;          // one S row (fp32)
    const size_t sb1 = 4096ull * srow_bytes;        // one batch of S

    // Plan: G = batches of S at once (z-grouped); else RC = row-chunk within a batch.
    int G = 0, RC = 0;
    if      (o_s + 8 * sb1 <= ws_size) G = 8;
    else if (o_s + 4 * sb1 <= ws_size) G = 4;
    else if (o_s + 2 * sb1 <= ws_size) G = 2;
    else if (o_s + 1 * sb1 <= ws_size) G = 1;
    else {
        for (int rc = 2048; rc >= 128; rc >>= 1)
            if (o_s + (size_t)rc * srow_bytes <= ws_size) { RC = rc; break; }
        if (!RC) {  // ws too small — diagnostic fallback
            copy_residual<<<dim3(2048), dim3(256), 0, stream>>>(x, out, (long)out_size);
            return;
        }
    }

    unsigned short* gwb = (unsigned short*)(ws + o_gwb);
    unsigned short* wwb = (unsigned short*)(ws + o_wwb);
    float* bnA = (float*)(ws + o_bnA);
    float* bnB = (float*)(ws + o_bnB);
    unsigned short* Qhl = (unsigned short*)(ws + o_q);
    unsigned short* Khl = (unsigned short*)(ws + o_k);
    unsigned short* Gp  = (unsigned short*)(ws + o_gp);
    unsigned short* Y   = (unsigned short*)(ws + o_y);
    float* S = (float*)(ws + o_s);

    prep_w<<<dim3(512), dim3(256), 0, stream>>>(g_w, W_w, W_b, gamma, beta, mean, var,
                                                gwb, wwb, bnA, bnB);
    build_q<<<dim3(128, 16, 8), dim3(32, 8), 0, stream>>>(x, Qhl);
    build_k<<<dim3(32, 16, 8), dim3(32, 8), 0, stream>>>(x, Khl);

    // G-conv: Gt[b][p][ci] (bf16, into Y slot) = Qhl_hi · gwb^T   (M=4096,N=256,K=512)
    gemm_abt<1, 0, 0><<<dim3(2, 32, 8), dim3(256), 0, stream>>>(
        Qhl, 1024, 4096l * 1024,
        gwb, 512, 0,
        (void*)Y, 256, 4096l * 256, 512,
        nullptr, nullptr, nullptr, 0);

    build_v<<<dim3(32, 32, 8), dim3(256), 0, stream>>>(Y, g_b, Gp);

    if (G) {
        for (int bg = 0; bg < 8; bg += G) {
            // QK^T with hi/lo split via virtual K=1536:
            //  j<512: qh*kh ; 512<=j<1024: qh*kl ; j>=1024: ql*kh
            gemm_abt<0, 512, 1024><<<dim3(8, 32, G), dim3(256), 0, stream>>>(
                Qhl + (size_t)bg * 4096 * 1024, 1024, 4096l * 1024,
                Khl + (size_t)bg * 1024 * 1024, 1024, 1024l * 1024,
                (void*)S, 1024, 4096l * 1024, 1536,
                nullptr, nullptr, nullptr, 0);
            softmax_rows<<<dim3(G * 4096), dim3(256), 0, stream>>>(S);
            // PV: Y[b][q][ci] = P · Gp^T   (M=4096,N=256,K=1024); P bf16 rows inside S
            gemm_abt<1, 0, 0><<<dim3(2, 32, G), dim3(256), 0, stream>>>(
                (const unsigned short*)S, 2048, 4096l * 2048,
                Gp + (size_t)bg * 256 * 1024, 1024, 256l * 1024,
                (void*)(Y + (size_t)bg * 4096 * 256), 256, 4096l * 256, 1024,
                nullptr, nullptr, nullptr, 0);
        }
    } else {
        // Row-chunked path (small workspace): S holds RC rows at a time.
        for (int b = 0; b < 8; b++) {
            for (int r0 = 0; r0 < 4096; r0 += RC) {
                const unsigned short* Aq = Qhl + (size_t)b * 4096 * 1024 + (size_t)r0 * 1024;
                gemm_abt<0, 512, 1024><<<dim3(8, RC / 128, 1), dim3(256), 0, stream>>>(
                    Aq, 1024, 0,
                    Khl + (size_t)b * 1024 * 1024, 1024, 0,
                    (void*)S, 1024, 0, 1536,
                    nullptr, nullptr, nullptr, 0);
                softmax_rows<<<dim3(RC), dim3(256), 0, stream>>>(S);
                gemm_abt<1, 0, 0><<<dim3(2, RC / 128, 1), dim3(256), 0, stream>>>(
                    (const unsigned short*)S, 2048, 0,
                    Gp + (size_t)b * 256 * 1024, 1024, 0,
                    (void*)(Y + ((size_t)b * 4096 + r0) * 256), 256, 0, 1024,
                    nullptr, nullptr, nullptr, 0);
            }
        }
    }

    // W-conv + BN + residual: out[b][o][p] = (wwb·Y^T)*bnA[o]+bnB[o]+x  (M=512,N=4096,K=256)
    gemm_abt<2, 0, 0><<<dim3(32, 4, 8), dim3(256), 0, stream>>>(
        wwb, 256, 0,
        Y, 256, 4096l * 256,
        (void*)out, 4096, 512l * 4096, 256,
        bnA, bnB, x, 512l * 4096);
}

// Round 5
// 216.826 us; speedup vs baseline: 1.5613x; 1.5055x over previous
//
#include <hip/hip_runtime.h>
#include <stdint.h>

typedef __attribute__((ext_vector_type(4))) float f32x4;
typedef __attribute__((ext_vector_type(8))) short short8_t;     // 8 bf16 for MFMA operand
typedef __attribute__((ext_vector_type(8))) unsigned short ushort8_t;

__device__ __forceinline__ unsigned short f2bf(float f) {
    unsigned int u = __builtin_bit_cast(unsigned int, f);
    u = (u + 0x7fffu + ((u >> 16) & 1u)) >> 16;   // round-to-nearest-even
    return (unsigned short)u;
}
__device__ __forceinline__ float bf2f(unsigned short h) {
    unsigned int u = ((unsigned int)h) << 16;
    return __builtin_bit_cast(float, u);
}

// async global->LDS, 16B per lane. LDS dest = wave-uniform base + lane*16.
__device__ __forceinline__ void gll16(const unsigned short* g, unsigned short* l) {
    __builtin_amdgcn_global_load_lds(
        (const __attribute__((address_space(1))) void*)g,
        (__attribute__((address_space(3))) void*)l, 16, 0, 0);
}

// ---------------------------------------------------------------- prep weights
__global__ __launch_bounds__(256) void prep_w(
    const float* __restrict__ g_w, const float* __restrict__ W_w,
    const float* __restrict__ W_b, const float* __restrict__ gamma,
    const float* __restrict__ beta, const float* __restrict__ mean,
    const float* __restrict__ var,
    unsigned short* __restrict__ gwb, unsigned short* __restrict__ wwb,
    float* __restrict__ bnA, float* __restrict__ bnB)
{
    int i = blockIdx.x * 256 + threadIdx.x;
    if (i < 256 * 512) { gwb[i] = f2bf(g_w[i]); wwb[i] = f2bf(W_w[i]); }
    if (i < 512) {
        float is = rsqrtf(var[i] + 1e-5f);
        float a = gamma[i] * is;
        bnA[i] = a;
        bnB[i] = (W_b[i] - mean[i]) * a + beta[i];
    }
}

// ------------------------------------------------- Qh: X^T transpose to bf16
// Qh[b][q][512].  grid (4096/32, 512/32, 8), block (32,8)
__global__ void build_q(const float* __restrict__ x, unsigned short* __restrict__ Qh)
{
    __shared__ float t[32][33];
    int b = blockIdx.z, p0 = blockIdx.x * 32, c0 = blockIdx.y * 32;
    const float* xb = x + (long)b * 512 * 4096;
    int tx = threadIdx.x, ty = threadIdx.y;
    for (int i = 0; i < 4; i++)
        t[ty + i * 8][tx] = xb[(long)(c0 + ty + i * 8) * 4096 + p0 + tx];
    __syncthreads();
    unsigned short* qb = Qh + (long)b * 4096 * 512;
    for (int i = 0; i < 4; i++) {
        float v = t[tx][ty + i * 8];
        long row = (long)(p0 + ty + i * 8) * 512;
        qb[row + c0 + tx] = f2bf(v);
    }
}

// --------------------------------- Kh: maxpool(x) transpose to bf16
// Kh[b][k'][512].  grid (1024/32, 512/32, 8), block (32,8)
__global__ void build_k(const float* __restrict__ x, unsigned short* __restrict__ Kh)
{
    __shared__ float t[32][33];
    int b = blockIdx.z, k0 = blockIdx.x * 32, c0 = blockIdx.y * 32;
    const float* xb = x + (long)b * 512 * 4096;
    int tx = threadIdx.x, ty = threadIdx.y;
    for (int i = 0; i < 4; i++) {
        int c = c0 + ty + i * 8;
        int k = k0 + tx;
        int h = k >> 5, w = k & 31;
        const float* base = xb + (long)c * 4096 + h * 128 + w * 2;
        float v = fmaxf(fmaxf(base[0], base[1]), fmaxf(base[64], base[65]));
        t[ty + i * 8][tx] = v;
    }
    __syncthreads();
    unsigned short* kb = Kh + (long)b * 1024 * 512;
    for (int i = 0; i < 4; i++) {
        float v = t[tx][ty + i * 8];
        long row = (long)(k0 + ty + i * 8) * 512;
        kb[row + c0 + tx] = f2bf(v);
    }
}

// ---------------- V build: Gp[b][ci][k'] = bf16(g_b[ci] + maxpool2(Gt)[ci][k'])
// Gt is bf16 [b][p=4096][ci=256].  grid (1024/32, 256/8, 8), block 256
__global__ __launch_bounds__(256) void build_v(
    const unsigned short* __restrict__ Gt, const float* __restrict__ g_b,
    unsigned short* __restrict__ Gp)
{
    int b = blockIdx.z;
    int k  = blockIdx.x * 32 + (threadIdx.x & 31);
    int ci = blockIdx.y * 8 + (threadIdx.x >> 5);
    int h = k >> 5, w = k & 31;
    const unsigned short* g = Gt + (long)b * 4096 * 256;
    long p = (long)(h * 128 + w * 2) * 256 + ci;
    float v0 = bf2f(g[p]),        v1 = bf2f(g[p + 256]);
    float v2 = bf2f(g[p + 64*256]), v3 = bf2f(g[p + 65*256]);
    float v = fmaxf(fmaxf(v0, v1), fmaxf(v2, v3)) + g_b[ci];
    Gp[(long)b * 256 * 1024 + (long)ci * 1024 + k] = f2bf(v);
}

// ----------------------- softmax over rows of 1024, in-place P (bf16) at row start
__global__ __launch_bounds__(256) void softmax_rows(float* __restrict__ S)
{
    long row = blockIdx.x;
    float* r = S + row * 1024;
    int tid = threadIdx.x;
    float4 v = ((const float4*)r)[tid];
    float m = fmaxf(fmaxf(v.x, v.y), fmaxf(v.z, v.w));
    for (int off = 32; off; off >>= 1) m = fmaxf(m, __shfl_xor(m, off));
    __shared__ float redm[4], reds[4];
    int wid = tid >> 6, lane = tid & 63;
    if (lane == 0) redm[wid] = m;
    __syncthreads();
    m = fmaxf(fmaxf(redm[0], redm[1]), fmaxf(redm[2], redm[3]));
    float e0 = __expf(v.x - m), e1 = __expf(v.y - m);
    float e2 = __expf(v.z - m), e3 = __expf(v.w - m);
    float s = e0 + e1 + e2 + e3;
    for (int off = 32; off; off >>= 1) s += __shfl_xor(s, off);
    if (lane == 0) reds[wid] = s;
    __syncthreads();
    s = reds[0] + reds[1] + reds[2] + reds[3];
    float inv = 1.0f / s;
    ushort4 p;
    p.x = f2bf(e0 * inv); p.y = f2bf(e1 * inv);
    p.z = f2bf(e2 * inv); p.w = f2bf(e3 * inv);
    ((ushort4*)r)[tid] = p;   // first 2KB of the 4KB row
}

// -------------------------------------------------------------------- GEMM
// C[m][n] = sum_k A[m][k]*B[n][k]  (A row-major along k, B row-major along k)
// 128x128 tile, BK=64, 256 threads = 4 waves in 2x2, each wave 64x64 out.
// Staging: global_load_lds dwordx4, linear LDS dest, XOR-swizzled global source;
// read side applies the same XOR (rule #21: both-sides-or-neither).
// Block index is XCD-remapped (T1) when nwg%8==0.
// AFOLD/BFOLD: virtual-K region fold (k0 >= FOLD -> k0-FOLD); unused this round.
// EPI: 0 = f32 store, 1 = bf16 store, 2 = v*bnA[m]+bnB[m]+Xres then f32 store.
template<int EPI, int AFOLD, int BFOLD>
__global__ __launch_bounds__(256) void gemm_abt(
    const unsigned short* __restrict__ A, int lda, long abstr,
    const unsigned short* __restrict__ B, int ldb, long bbstr,
    void* __restrict__ Cv, int ldc, long cbstr,
    int K,
    const float* __restrict__ bnA, const float* __restrict__ bnB,
    const float* __restrict__ Xres, long xbstr)
{
    __shared__ unsigned short lA[128 * 64];
    __shared__ unsigned short lB[128 * 64];
    const int tid = threadIdx.x;
    const int wid = tid >> 6, lane = tid & 63;

    // ---- XCD-aware block remap (bijective; identity if nwg%8 != 0)
    unsigned gx = gridDim.x, gy = gridDim.y;
    unsigned nwg = gx * gy * gridDim.z;
    unsigned lin = blockIdx.x + gx * (blockIdx.y + gy * blockIdx.z);
    unsigned l = ((nwg & 7u) == 0u) ? ((lin & 7u) * (nwg >> 3) + (lin >> 3)) : lin;
    unsigned bx = l % gx;
    unsigned rem = l / gx;
    unsigned by = rem % gy;
    unsigned bz = rem / gy;

    const int z = (int)bz;
    const int m0 = (int)by * 128, n0 = (int)bx * 128;
    const unsigned short* Ab = A + z * abstr;
    const unsigned short* Bb = B + z * bbstr;
    const int wr = wid >> 1, wc = wid & 1;
    const int lr = lane & 15, lg = lane >> 4;

    // staging geometry: instr i covers 8 rows starting at i*32 + wid*8;
    // lane l -> row (l>>3) in group, source chunk (l&7)^(l>>3) (XOR pre-swizzle)
    const int srA = lane >> 3;                         // 0..7
    const int scg = (((lane & 7) ^ srA) << 3);         // element offset 0..56

    f32x4 acc[4][4];
    for (int mi = 0; mi < 4; mi++)
        for (int ni = 0; ni < 4; ni++)
            acc[mi][ni] = (f32x4){0.f, 0.f, 0.f, 0.f};

    for (int k0 = 0; k0 < K; k0 += 64) {
        int ak0 = (AFOLD && k0 >= AFOLD) ? k0 - AFOLD : k0;
        int bk0 = (BFOLD && k0 >= BFOLD) ? k0 - BFOLD : k0;
        __syncthreads();   // previous iter's LDS reads complete
        for (int i = 0; i < 4; i++) {
            int rowbase = i * 32 + wid * 8;
            gll16(Ab + (long)(m0 + rowbase + srA) * lda + ak0 + scg, &lA[rowbase * 64]);
            gll16(Bb + (long)(n0 + rowbase + srA) * ldb + bk0 + scg, &lB[rowbase * 64]);
        }
        __syncthreads();   // drains vmcnt(0): tiles resident
        for (int kk = 0; kk < 2; kk++) {
            short8_t af[4], bf[4];
            for (int mi = 0; mi < 4; mi++) {
                int row = wr * 64 + mi * 16 + lr;
                int ch = ((kk * 4 + lg) ^ (row & 7)) * 8;
                af[mi] = *(const short8_t*)(&lA[row * 64 + ch]);
            }
            for (int ni = 0; ni < 4; ni++) {
                int row = wc * 64 + ni * 16 + lr;
                int ch = ((kk * 4 + lg) ^ (row & 7)) * 8;
                bf[ni] = *(const short8_t*)(&lB[row * 64 + ch]);
            }
            for (int mi = 0; mi < 4; mi++)
                for (int ni = 0; ni < 4; ni++)
                    acc[mi][ni] = __builtin_amdgcn_mfma_f32_16x16x32_bf16(
                        af[mi], bf[ni], acc[mi][ni], 0, 0, 0);
        }
    }

    // epilogue: lane holds D[row=(lane>>4)*4+r][col=lane&15]
    for (int mi = 0; mi < 4; mi++) {
        for (int ni = 0; ni < 4; ni++) {
            int ncol = n0 + wc * 64 + ni * 16 + lr;
            int mrow = m0 + wr * 64 + mi * 16 + lg * 4;
            for (int r = 0; r < 4; r++) {
                int row = mrow + r;
                float v = acc[mi][ni][r];
                long idx = z * cbstr + (long)row * ldc + ncol;
                if (EPI == 0) {
                    ((float*)Cv)[idx] = v;
                } else if (EPI == 1) {
                    ((unsigned short*)Cv)[idx] = f2bf(v);
                } else {
                    float o = v * bnA[row] + bnB[row] + Xres[z * xbstr + (long)row * ldc + ncol];
                    ((float*)Cv)[idx] = o;
                }
            }
        }
    }
}

// fallback if workspace too small (diagnostic: out = x)
__global__ void copy_residual(const float* __restrict__ x, float* __restrict__ out, long n)
{
    for (long i = blockIdx.x * 256ll + threadIdx.x; i < n; i += (long)gridDim.x * 256)
        out[i] = x[i];
}

extern "C" void kernel_launch(void* const* d_in, const int* in_sizes, int n_in,
                              void* d_out, int out_size, void* d_ws, size_t ws_size,
                              hipStream_t stream)
{
    const float* x     = (const float*)d_in[0];
    const float* g_w   = (const float*)d_in[1];
    const float* g_b   = (const float*)d_in[2];
    const float* W_w   = (const float*)d_in[3];
    const float* W_b   = (const float*)d_in[4];
    const float* gamma = (const float*)d_in[5];
    const float* beta  = (const float*)d_in[6];
    const float* mean  = (const float*)d_in[7];
    const float* var   = (const float*)d_in[8];
    float* out = (float*)d_out;

    char* ws = (char*)d_ws;
    size_t o = 0;
    auto alloc = [&](size_t bytes) { size_t r = o; o = (o + bytes + 255) & ~(size_t)255; return r; };
    size_t o_gwb = alloc(256 * 512 * 2);
    size_t o_wwb = alloc(512 * 256 * 2);
    size_t o_bnA = alloc(512 * 4);
    size_t o_bnB = alloc(512 * 4);
    size_t o_q   = alloc(8ull * 4096 * 512 * 2);   // Qh bf16
    size_t o_k   = alloc(8ull * 1024 * 512 * 2);   // Kh bf16
    size_t o_gp  = alloc(8ull * 256 * 1024 * 2);   // V^T (pooled g, bf16)
    size_t o_y   = alloc(8ull * 4096 * 256 * 2);   // Y (also holds Gt before pooling)
    size_t o_s   = o;                               // S fp32 (P bf16 in-place)
    const size_t srow_bytes = 1024ull * 4;          // one S row (fp32)
    const size_t sb1 = 4096ull * srow_bytes;        // one batch of S

    // Plan: G = batches of S at once (z-grouped); else RC = row-chunk within a batch.
    int G = 0, RC = 0;
    if      (o_s + 8 * sb1 <= ws_size) G = 8;
    else if (o_s + 4 * sb1 <= ws_size) G = 4;
    else if (o_s + 2 * sb1 <= ws_size) G = 2;
    else if (o_s + 1 * sb1 <= ws_size) G = 1;
    else {
        for (int rc = 2048; rc >= 128; rc >>= 1)
            if (o_s + (size_t)rc * srow_bytes <= ws_size) { RC = rc; break; }
        if (!RC) {  // ws too small — diagnostic fallback
            copy_residual<<<dim3(2048), dim3(256), 0, stream>>>(x, out, (long)out_size);
            return;
        }
    }

    unsigned short* gwb = (unsigned short*)(ws + o_gwb);
    unsigned short* wwb = (unsigned short*)(ws + o_wwb);
    float* bnA = (float*)(ws + o_bnA);
    float* bnB = (float*)(ws + o_bnB);
    unsigned short* Qh  = (unsigned short*)(ws + o_q);
    unsigned short* Kh  = (unsigned short*)(ws + o_k);
    unsigned short* Gp  = (unsigned short*)(ws + o_gp);
    unsigned short* Y   = (unsigned short*)(ws + o_y);
    float* S = (float*)(ws + o_s);

    prep_w<<<dim3(512), dim3(256), 0, stream>>>(g_w, W_w, W_b, gamma, beta, mean, var,
                                                gwb, wwb, bnA, bnB);
    build_q<<<dim3(128, 16, 8), dim3(32, 8), 0, stream>>>(x, Qh);
    build_k<<<dim3(32, 16, 8), dim3(32, 8), 0, stream>>>(x, Kh);

    // G-conv: Gt[b][p][ci] (bf16, into Y slot) = Qh · gwb^T   (M=4096,N=256,K=512)
    gemm_abt<1, 0, 0><<<dim3(2, 32, 8), dim3(256), 0, stream>>>(
        Qh, 512, 4096l * 512,
        gwb, 512, 0,
        (void*)Y, 256, 4096l * 256, 512,
        nullptr, nullptr, nullptr, 0);

    build_v<<<dim3(32, 32, 8), dim3(256), 0, stream>>>(Y, g_b, Gp);

    if (G) {
        for (int bg = 0; bg < 8; bg += G) {
            // QK^T: plain bf16, K=512
            gemm_abt<0, 0, 0><<<dim3(8, 32, G), dim3(256), 0, stream>>>(
                Qh + (size_t)bg * 4096 * 512, 512, 4096l * 512,
                Kh + (size_t)bg * 1024 * 512, 512, 1024l * 512,
                (void*)S, 1024, 4096l * 1024, 512,
                nullptr, nullptr, nullptr, 0);
            softmax_rows<<<dim3(G * 4096), dim3(256), 0, stream>>>(S);
            // PV: Y[b][q][ci] = P · Gp^T   (M=4096,N=256,K=1024); P bf16 rows inside S
            gemm_abt<1, 0, 0><<<dim3(2, 32, G), dim3(256), 0, stream>>>(
                (const unsigned short*)S, 2048, 4096l * 2048,
                Gp + (size_t)bg * 256 * 1024, 1024, 256l * 1024,
                (void*)(Y + (size_t)bg * 4096 * 256), 256, 4096l * 256, 1024,
                nullptr, nullptr, nullptr, 0);
        }
    } else {
        // Row-chunked path (small workspace): S holds RC rows at a time.
        for (int b = 0; b < 8; b++) {
            for (int r0 = 0; r0 < 4096; r0 += RC) {
                const unsigned short* Aq = Qh + (size_t)b * 4096 * 512 + (size_t)r0 * 512;
                gemm_abt<0, 0, 0><<<dim3(8, RC / 128, 1), dim3(256), 0, stream>>>(
                    Aq, 512, 0,
                    Kh + (size_t)b * 1024 * 512, 512, 0,
                    (void*)S, 1024, 0, 512,
                    nullptr, nullptr, nullptr, 0);
                softmax_rows<<<dim3(RC), dim3(256), 0, stream>>>(S);
                gemm_abt<1, 0, 0><<<dim3(2, RC / 128, 1), dim3(256), 0, stream>>>(
                    (const unsigned short*)S, 2048, 0,
                    Gp + (size_t)b * 256 * 1024, 1024, 0,
                    (void*)(Y + ((size_t)b * 4096 + r0) * 256), 256, 0, 1024,
                    nullptr, nullptr, nullptr, 0);
            }
        }
    }

    // W-conv + BN + residual: out[b][o][p] = (wwb·Y^T)*bnA[o]+bnB[o]+x  (M=512,N=4096,K=256)
    gemm_abt<2, 0, 0><<<dim3(32, 4, 8), dim3(256), 0, stream>>>(
        wwb, 256, 0,
        Y, 256, 4096l * 256,
        (void*)out, 4096, 512l * 4096, 256,
        bnA, bnB, x, 512l * 4096);
}

// Round 7
// 195.240 us; speedup vs baseline: 1.7339x; 1.1106x over previous
//
#include <hip/hip_runtime.h>
#include <stdint.h>

typedef __attribute__((ext_vector_type(4))) float f32x4;
typedef __attribute__((ext_vector_type(8))) short short8_t;     // 8 bf16 for MFMA operand
typedef __attribute__((ext_vector_type(8))) unsigned short ushort8_t;

__device__ __forceinline__ unsigned short f2bf(float f) {
    unsigned int u = __builtin_bit_cast(unsigned int, f);
    u = (u + 0x7fffu + ((u >> 16) & 1u)) >> 16;   // round-to-nearest-even
    return (unsigned short)u;
}
__device__ __forceinline__ float bf2f(unsigned short h) {
    unsigned int u = ((unsigned int)h) << 16;
    return __builtin_bit_cast(float, u);
}

// async global->LDS, 16B per lane. LDS dest = wave-uniform base + lane*16.
__device__ __forceinline__ void gll16(const unsigned short* g, unsigned short* l) {
    __builtin_amdgcn_global_load_lds(
        (const __attribute__((address_space(1))) void*)g,
        (__attribute__((address_space(3))) void*)l, 16, 0, 0);
}

// ---------------------------------------------------------------- prep weights
__global__ __launch_bounds__(256) void prep_w(
    const float* __restrict__ g_w, const float* __restrict__ W_w,
    const float* __restrict__ W_b, const float* __restrict__ gamma,
    const float* __restrict__ beta, const float* __restrict__ mean,
    const float* __restrict__ var,
    unsigned short* __restrict__ gwb, unsigned short* __restrict__ wwb,
    float* __restrict__ bnA, float* __restrict__ bnB)
{
    int i = blockIdx.x * 256 + threadIdx.x;
    if (i < 256 * 512) { gwb[i] = f2bf(g_w[i]); wwb[i] = f2bf(W_w[i]); }
    if (i < 512) {
        float is = rsqrtf(var[i] + 1e-5f);
        float a = gamma[i] * is;
        bnA[i] = a;
        bnB[i] = (W_b[i] - mean[i]) * a + beta[i];
    }
}

// ------------------------------------------------- Qh: X^T transpose to bf16
// Qh[b][q][512].  grid (4096/32, 512/32, 8), block (32,8)
__global__ void build_q(const float* __restrict__ x, unsigned short* __restrict__ Qh)
{
    __shared__ float t[32][33];
    int b = blockIdx.z, p0 = blockIdx.x * 32, c0 = blockIdx.y * 32;
    const float* xb = x + (long)b * 512 * 4096;
    int tx = threadIdx.x, ty = threadIdx.y;
    for (int i = 0; i < 4; i++)
        t[ty + i * 8][tx] = xb[(long)(c0 + ty + i * 8) * 4096 + p0 + tx];
    __syncthreads();
    unsigned short* qb = Qh + (long)b * 4096 * 512;
    for (int i = 0; i < 4; i++) {
        float v = t[tx][ty + i * 8];
        long row = (long)(p0 + ty + i * 8) * 512;
        qb[row + c0 + tx] = f2bf(v);
    }
}

// --------------------------------- Kh: maxpool(x) transpose to bf16
// Kh[b][k'][512].  grid (1024/32, 512/32, 8), block (32,8)
__global__ void build_k(const float* __restrict__ x, unsigned short* __restrict__ Kh)
{
    __shared__ float t[32][33];
    int b = blockIdx.z, k0 = blockIdx.x * 32, c0 = blockIdx.y * 32;
    const float* xb = x + (long)b * 512 * 4096;
    int tx = threadIdx.x, ty = threadIdx.y;
    for (int i = 0; i < 4; i++) {
        int c = c0 + ty + i * 8;
        int k = k0 + tx;
        int h = k >> 5, w = k & 31;
        const float* base = xb + (long)c * 4096 + h * 128 + w * 2;
        float v = fmaxf(fmaxf(base[0], base[1]), fmaxf(base[64], base[65]));
        t[ty + i * 8][tx] = v;
    }
    __syncthreads();
    unsigned short* kb = Kh + (long)b * 1024 * 512;
    for (int i = 0; i < 4; i++) {
        float v = t[tx][ty + i * 8];
        long row = (long)(k0 + ty + i * 8) * 512;
        kb[row + c0 + tx] = f2bf(v);
    }
}

// ---------------- V build: Gp[b][ci][k'] = bf16(g_b[ci] + maxpool2(Gt)[ci][k'])
// Gt is bf16 [b][p=4096][ci=256].  grid (1024/32, 256/8, 8), block 256
__global__ __launch_bounds__(256) void build_v(
    const unsigned short* __restrict__ Gt, const float* __restrict__ g_b,
    unsigned short* __restrict__ Gp)
{
    int b = blockIdx.z;
    int k  = blockIdx.x * 32 + (threadIdx.x & 31);
    int ci = blockIdx.y * 8 + (threadIdx.x >> 5);
    int h = k >> 5, w = k & 31;
    const unsigned short* g = Gt + (long)b * 4096 * 256;
    long p = (long)(h * 128 + w * 2) * 256 + ci;
    float v0 = bf2f(g[p]),        v1 = bf2f(g[p + 256]);
    float v2 = bf2f(g[p + 64*256]), v3 = bf2f(g[p + 65*256]);
    float v = fmaxf(fmaxf(v0, v1), fmaxf(v2, v3)) + g_b[ci];
    Gp[(long)b * 256 * 1024 + (long)ci * 1024 + k] = f2bf(v);
}

// ------------------------------------------- fused softmax + PV
// Per block: 64 q-rows, full 1024 keys, full 256 ci.
// S bf16 logits [rows][1024]; Gp bf16 [256][1024]; Y bf16 [rows][256].
// Pass 1: online row max+sum.  Pass 2: per 64-key block, P=exp(s-m) -> LDS
// (XOR chunk swizzle), V tile via global_load_lds, MFMA; 1/l in epilogue.
__global__ __launch_bounds__(256) void pv_fused(
    const unsigned short* __restrict__ S, long sbstr,
    const unsigned short* __restrict__ Gp, long gbstr,
    unsigned short* __restrict__ Y, long ybstr)
{
    __shared__ unsigned short lV[256 * 64];   // 32 KB
    __shared__ unsigned short lP[64 * 64];    // 8 KB
    __shared__ float pm[256], pl[256];
    __shared__ float lm[64], li[64];

    const int tid = threadIdx.x;
    const int wid = tid >> 6, lane = tid & 63;

    // XCD-aware remap: batch (blockIdx.y) groups land on one XCD
    unsigned gx = gridDim.x, gy = gridDim.y;
    unsigned nwg = gx * gy;
    unsigned lin = blockIdx.x + gx * blockIdx.y;
    unsigned l = ((nwg & 7u) == 0u) ? ((lin & 7u) * (nwg >> 3) + (lin >> 3)) : lin;
    unsigned bx = l % gx, by = l / gx;

    const int q0 = (int)bx * 64;
    const unsigned short* Sb = S + by * sbstr + (long)q0 * 1024;
    const unsigned short* Gb = Gp + by * gbstr;
    unsigned short* Yb = Y + by * ybstr + (long)q0 * 256;

    // ---- pass 1: per-row max and sum(exp) over 1024 keys (4 threads/row)
    {
        int r = tid >> 2, qq = tid & 3;
        const unsigned short* p = Sb + (long)r * 1024 + qq * 256;
        float m = -3.0e38f, s = 0.f;
        for (int i = 0; i < 32; i++) {
            ushort8_t v = *(const ushort8_t*)(p + i * 8);
            float f0 = bf2f(v[0]), f1 = bf2f(v[1]), f2 = bf2f(v[2]), f3 = bf2f(v[3]);
            float f4 = bf2f(v[4]), f5 = bf2f(v[5]), f6 = bf2f(v[6]), f7 = bf2f(v[7]);
            float cm = fmaxf(fmaxf(fmaxf(f0, f1), fmaxf(f2, f3)),
                             fmaxf(fmaxf(f4, f5), fmaxf(f6, f7)));
            if (cm > m) { s *= __expf(m - cm); m = cm; }
            s += __expf(f0 - m) + __expf(f1 - m) + __expf(f2 - m) + __expf(f3 - m)
               + __expf(f4 - m) + __expf(f5 - m) + __expf(f6 - m) + __expf(f7 - m);
        }
        pm[tid] = m; pl[tid] = s;
    }
    __syncthreads();
    if (tid < 64) {
        float m0 = pm[tid*4], m1 = pm[tid*4+1], m2 = pm[tid*4+2], m3 = pm[tid*4+3];
        float m = fmaxf(fmaxf(m0, m1), fmaxf(m2, m3));
        float s = pl[tid*4]   * __expf(m0 - m) + pl[tid*4+1] * __expf(m1 - m)
                + pl[tid*4+2] * __expf(m2 - m) + pl[tid*4+3] * __expf(m3 - m);
        lm[tid] = m; li[tid] = 1.0f / s;
    }

    const int wr = wid >> 1, wc = wid & 1;
    const int lr = lane & 15, lg = lane >> 4;
    const int srA = lane >> 3;
    const int scg = (((lane & 7) ^ srA) << 3);
    const int pr = tid >> 2;            // lP row 0..63
    const int pc = (tid & 3) * 2;       // chunk base (2 chunks of 8 keys)

    f32x4 acc[2][8];
    for (int mi = 0; mi < 2; mi++)
        for (int ni = 0; ni < 8; ni++)
            acc[mi][ni] = (f32x4){0.f, 0.f, 0.f, 0.f};

    for (int kb = 0; kb < 16; kb++) {
        __syncthreads();   // prev MFMA reads done; lm/li ready at kb=0
        // stage V tile [256 ci][64 keys] (linear LDS dest, pre-swizzled source)
        for (int i = 0; i < 8; i++) {
            int cibase = i * 32 + wid * 8;
            gll16(Gb + (long)(cibase + srA) * 1024 + kb * 64 + scg, &lV[cibase * 64]);
        }
        // P chunk: p = exp(s - m) -> bf16 -> lP (XOR chunk swizzle); overlaps DMA
        {
            float m = lm[pr];
            const unsigned short* sp = Sb + (long)pr * 1024 + kb * 64 + pc * 8;
            for (int j = 0; j < 2; j++) {
                ushort8_t v = *(const ushort8_t*)(sp + j * 8);
                ushort8_t o8;
                for (int e = 0; e < 8; e++) o8[e] = f2bf(__expf(bf2f(v[e]) - m));
                int c = pc + j;
                *(ushort8_t*)(&lP[pr * 64 + ((c ^ (pr & 7)) * 8)]) = o8;
            }
        }
        __syncthreads();   // drains vmcnt(0) + LDS writes
        for (int ks = 0; ks < 2; ks++) {
            short8_t af[2], bfr[8];
            for (int mi = 0; mi < 2; mi++) {
                int row = wr * 32 + mi * 16 + lr;
                int ch = ((ks * 4 + lg) ^ (row & 7)) * 8;
                af[mi] = *(const short8_t*)(&lP[row * 64 + ch]);
            }
            for (int ni = 0; ni < 8; ni++) {
                int row = wc * 128 + ni * 16 + lr;
                int ch = ((ks * 4 + lg) ^ (row & 7)) * 8;
                bfr[ni] = *(const short8_t*)(&lV[row * 64 + ch]);
            }
            for (int mi = 0; mi < 2; mi++)
                for (int ni = 0; ni < 8; ni++)
                    acc[mi][ni] = __builtin_amdgcn_mfma_f32_16x16x32_bf16(
                        af[mi], bfr[ni], acc[mi][ni], 0, 0, 0);
        }
    }

    // epilogue: Y[row][ci] = bf16(acc * 1/l)
    for (int mi = 0; mi < 2; mi++) {
        for (int ni = 0; ni < 8; ni++) {
            int ci = wc * 128 + ni * 16 + lr;
            int rbase = wr * 32 + mi * 16 + lg * 4;
            for (int r = 0; r < 4; r++) {
                int row = rbase + r;
                Yb[(long)row * 256 + ci] = f2bf(acc[mi][ni][r] * li[row]);
            }
        }
    }
}

// -------------------------------------------------------------------- GEMM
// C[m][n] = sum_k A[m][k]*B[n][k]  (A row-major along k, B row-major along k)
// 128x128 tile, BK=64, 256 threads = 4 waves in 2x2, each wave 64x64 out.
// Staging: global_load_lds dwordx4, linear LDS dest, XOR-swizzled global source;
// read side applies the same XOR (rule #21: both-sides-or-neither).
// Block index is XCD-remapped (T1) when nwg%8==0.
// EPI: 0 = f32 store, 1 = bf16 store, 2 = v*bnA[m]+bnB[m]+Xres then f32 store.
template<int EPI, int AFOLD, int BFOLD>
__global__ __launch_bounds__(256) void gemm_abt(
    const unsigned short* __restrict__ A, int lda, long abstr,
    const unsigned short* __restrict__ B, int ldb, long bbstr,
    void* __restrict__ Cv, int ldc, long cbstr,
    int K,
    const float* __restrict__ bnA, const float* __restrict__ bnB,
    const float* __restrict__ Xres, long xbstr)
{
    __shared__ unsigned short lA[128 * 64];
    __shared__ unsigned short lB[128 * 64];
    const int tid = threadIdx.x;
    const int wid = tid >> 6, lane = tid & 63;

    // ---- XCD-aware block remap (bijective; identity if nwg%8 != 0)
    unsigned gx = gridDim.x, gy = gridDim.y;
    unsigned nwg = gx * gy * gridDim.z;
    unsigned lin = blockIdx.x + gx * (blockIdx.y + gy * blockIdx.z);
    unsigned l = ((nwg & 7u) == 0u) ? ((lin & 7u) * (nwg >> 3) + (lin >> 3)) : lin;
    unsigned bx = l % gx;
    unsigned rem = l / gx;
    unsigned by = rem % gy;
    unsigned bz = rem / gy;

    const int z = (int)bz;
    const int m0 = (int)by * 128, n0 = (int)bx * 128;
    const unsigned short* Ab = A + z * abstr;
    const unsigned short* Bb = B + z * bbstr;
    const int wr = wid >> 1, wc = wid & 1;
    const int lr = lane & 15, lg = lane >> 4;

    const int srA = lane >> 3;                         // 0..7
    const int scg = (((lane & 7) ^ srA) << 3);         // element offset 0..56

    f32x4 acc[4][4];
    for (int mi = 0; mi < 4; mi++)
        for (int ni = 0; ni < 4; ni++)
            acc[mi][ni] = (f32x4){0.f, 0.f, 0.f, 0.f};

    for (int k0 = 0; k0 < K; k0 += 64) {
        int ak0 = (AFOLD && k0 >= AFOLD) ? k0 - AFOLD : k0;
        int bk0 = (BFOLD && k0 >= BFOLD) ? k0 - BFOLD : k0;
        __syncthreads();   // previous iter's LDS reads complete
        for (int i = 0; i < 4; i++) {
            int rowbase = i * 32 + wid * 8;
            gll16(Ab + (long)(m0 + rowbase + srA) * lda + ak0 + scg, &lA[rowbase * 64]);
            gll16(Bb + (long)(n0 + rowbase + srA) * ldb + bk0 + scg, &lB[rowbase * 64]);
        }
        __syncthreads();   // drains vmcnt(0): tiles resident
        for (int kk = 0; kk < 2; kk++) {
            short8_t af[4], bfr[4];
            for (int mi = 0; mi < 4; mi++) {
                int row = wr * 64 + mi * 16 + lr;
                int ch = ((kk * 4 + lg) ^ (row & 7)) * 8;
                af[mi] = *(const short8_t*)(&lA[row * 64 + ch]);
            }
            for (int ni = 0; ni < 4; ni++) {
                int row = wc * 64 + ni * 16 + lr;
                int ch = ((kk * 4 + lg) ^ (row & 7)) * 8;
                bfr[ni] = *(const short8_t*)(&lB[row * 64 + ch]);
            }
            for (int mi = 0; mi < 4; mi++)
                for (int ni = 0; ni < 4; ni++)
                    acc[mi][ni] = __builtin_amdgcn_mfma_f32_16x16x32_bf16(
                        af[mi], bfr[ni], acc[mi][ni], 0, 0, 0);
        }
    }

    // epilogue: lane holds D[row=(lane>>4)*4+r][col=lane&15]
    for (int mi = 0; mi < 4; mi++) {
        for (int ni = 0; ni < 4; ni++) {
            int ncol = n0 + wc * 64 + ni * 16 + lr;
            int mrow = m0 + wr * 64 + mi * 16 + lg * 4;
            for (int r = 0; r < 4; r++) {
                int row = mrow + r;
                float v = acc[mi][ni][r];
                long idx = z * cbstr + (long)row * ldc + ncol;
                if (EPI == 0) {
                    ((float*)Cv)[idx] = v;
                } else if (EPI == 1) {
                    ((unsigned short*)Cv)[idx] = f2bf(v);
                } else {
                    float o = v * bnA[row] + bnB[row] + Xres[z * xbstr + (long)row * ldc + ncol];
                    ((float*)Cv)[idx] = o;
                }
            }
        }
    }
}

// fallback if workspace too small (diagnostic: out = x)
__global__ void copy_residual(const float* __restrict__ x, float* __restrict__ out, long n)
{
    for (long i = blockIdx.x * 256ll + threadIdx.x; i < n; i += (long)gridDim.x * 256)
        out[i] = x[i];
}

extern "C" void kernel_launch(void* const* d_in, const int* in_sizes, int n_in,
                              void* d_out, int out_size, void* d_ws, size_t ws_size,
                              hipStream_t stream)
{
    const float* x     = (const float*)d_in[0];
    const float* g_w   = (const float*)d_in[1];
    const float* g_b   = (const float*)d_in[2];
    const float* W_w   = (const float*)d_in[3];
    const float* W_b   = (const float*)d_in[4];
    const float* gamma = (const float*)d_in[5];
    const float* beta  = (const float*)d_in[6];
    const float* mean  = (const float*)d_in[7];
    const float* var   = (const float*)d_in[8];
    float* out = (float*)d_out;

    char* ws = (char*)d_ws;
    size_t o = 0;
    auto alloc = [&](size_t bytes) { size_t r = o; o = (o + bytes + 255) & ~(size_t)255; return r; };
    size_t o_gwb = alloc(256 * 512 * 2);
    size_t o_wwb = alloc(512 * 256 * 2);
    size_t o_bnA = alloc(512 * 4);
    size_t o_bnB = alloc(512 * 4);
    size_t o_q   = alloc(8ull * 4096 * 512 * 2);   // Qh bf16
    size_t o_k   = alloc(8ull * 1024 * 512 * 2);   // Kh bf16
    size_t o_gp  = alloc(8ull * 256 * 1024 * 2);   // V^T (pooled g, bf16)
    size_t o_y   = alloc(8ull * 4096 * 256 * 2);   // Y (also holds Gt before pooling)
    size_t o_s   = o;                               // S bf16 logits
    const size_t srow_bytes = 1024ull * 2;          // one S row (bf16)
    const size_t sb1 = 4096ull * srow_bytes;        // one batch of S (8 MB)

    // Plan: G = batches of S at once (z-grouped); else RC = row-chunk within a batch.
    int G = 0, RC = 0;
    if      (o_s + 8 * sb1 <= ws_size) G = 8;
    else if (o_s + 4 * sb1 <= ws_size) G = 4;
    else if (o_s + 2 * sb1 <= ws_size) G = 2;
    else if (o_s + 1 * sb1 <= ws_size) G = 1;
    else {
        for (int rc = 2048; rc >= 128; rc >>= 1)
            if (o_s + (size_t)rc * srow_bytes <= ws_size) { RC = rc; break; }
        if (!RC) {  // ws too small — diagnostic fallback
            copy_residual<<<dim3(2048), dim3(256), 0, stream>>>(x, out, (long)out_size);
            return;
        }
    }

    unsigned short* gwb = (unsigned short*)(ws + o_gwb);
    unsigned short* wwb = (unsigned short*)(ws + o_wwb);
    float* bnA = (float*)(ws + o_bnA);
    float* bnB = (float*)(ws + o_bnB);
    unsigned short* Qh  = (unsigned short*)(ws + o_q);
    unsigned short* Kh  = (unsigned short*)(ws + o_k);
    unsigned short* Gp  = (unsigned short*)(ws + o_gp);
    unsigned short* Y   = (unsigned short*)(ws + o_y);
    unsigned short* S   = (unsigned short*)(ws + o_s);

    prep_w<<<dim3(512), dim3(256), 0, stream>>>(g_w, W_w, W_b, gamma, beta, mean, var,
                                                gwb, wwb, bnA, bnB);
    build_q<<<dim3(128, 16, 8), dim3(32, 8), 0, stream>>>(x, Qh);
    build_k<<<dim3(32, 16, 8), dim3(32, 8), 0, stream>>>(x, Kh);

    // G-conv: Gt[b][p][ci] (bf16, into Y slot) = Qh · gwb^T   (M=4096,N=256,K=512)
    gemm_abt<1, 0, 0><<<dim3(2, 32, 8), dim3(256), 0, stream>>>(
        Qh, 512, 4096l * 512,
        gwb, 512, 0,
        (void*)Y, 256, 4096l * 256, 512,
        nullptr, nullptr, nullptr, 0);

    build_v<<<dim3(32, 32, 8), dim3(256), 0, stream>>>(Y, g_b, Gp);

    if (G) {
        for (int bg = 0; bg < 8; bg += G) {
            // QK^T: bf16 in, bf16 logits out (K=512)
            gemm_abt<1, 0, 0><<<dim3(8, 32, G), dim3(256), 0, stream>>>(
                Qh + (size_t)bg * 4096 * 512, 512, 4096l * 512,
                Kh + (size_t)bg * 1024 * 512, 512, 1024l * 512,
                (void*)S, 1024, 4096l * 1024, 512,
                nullptr, nullptr, nullptr, 0);
            // fused softmax + PV: Y[b][q][ci]
            pv_fused<<<dim3(64, G), dim3(256), 0, stream>>>(
                S, 4096l * 1024,
                Gp + (size_t)bg * 256 * 1024, 256l * 1024,
                Y + (size_t)bg * 4096 * 256, 4096l * 256);
        }
    } else {
        // Row-chunked path (small workspace): S holds RC rows at a time.
        for (int b = 0; b < 8; b++) {
            for (int r0 = 0; r0 < 4096; r0 += RC) {
                const unsigned short* Aq = Qh + (size_t)b * 4096 * 512 + (size_t)r0 * 512;
                gemm_abt<1, 0, 0><<<dim3(8, RC / 128, 1), dim3(256), 0, stream>>>(
                    Aq, 512, 0,
                    Kh + (size_t)b * 1024 * 512, 512, 0,
                    (void*)S, 1024, 0, 512,
                    nullptr, nullptr, nullptr, 0);
                pv_fused<<<dim3(RC / 64, 1), dim3(256), 0, stream>>>(
                    S, 0,
                    Gp + (size_t)b * 256 * 1024, 0,
                    Y + ((size_t)b * 4096 + r0) * 256, 0);
            }
        }
    }

    // W-conv + BN + residual: out[b][o][p] = (wwb·Y^T)*bnA[o]+bnB[o]+x  (M=512,N=4096,K=256)
    gemm_abt<2, 0, 0><<<dim3(32, 4, 8), dim3(256), 0, stream>>>(
        wwb, 256, 0,
        Y, 256, 4096l * 256,
        (void*)out, 4096, 512l * 4096, 256,
        bnA, bnB, x, 512l * 4096);
}

// Round 8
// 183.002 us; speedup vs baseline: 1.8499x; 1.0669x over previous
//
#include <hip/hip_runtime.h>
#include <stdint.h>

typedef __attribute__((ext_vector_type(4))) float f32x4;
typedef __attribute__((ext_vector_type(8))) short short8_t;     // 8 bf16 for MFMA operand
typedef __attribute__((ext_vector_type(8))) unsigned short ushort8_t;

__device__ __forceinline__ unsigned short f2bf(float f) {
    unsigned int u = __builtin_bit_cast(unsigned int, f);
    u = (u + 0x7fffu + ((u >> 16) & 1u)) >> 16;   // round-to-nearest-even
    return (unsigned short)u;
}
__device__ __forceinline__ float bf2f(unsigned short h) {
    unsigned int u = ((unsigned int)h) << 16;
    return __builtin_bit_cast(float, u);
}

// async global->LDS, 16B per lane. LDS dest = wave-uniform base + lane*16.
__device__ __forceinline__ void gll16(const unsigned short* g, unsigned short* l) {
    __builtin_amdgcn_global_load_lds(
        (const __attribute__((address_space(1))) void*)g,
        (__attribute__((address_space(3))) void*)l, 16, 0, 0);
}

// ---------------------------------------------------------------- prep weights
__global__ __launch_bounds__(256) void prep_w(
    const float* __restrict__ g_w, const float* __restrict__ W_w,
    const float* __restrict__ W_b, const float* __restrict__ gamma,
    const float* __restrict__ beta, const float* __restrict__ mean,
    const float* __restrict__ var,
    unsigned short* __restrict__ gwb, unsigned short* __restrict__ wwb,
    float* __restrict__ bnA, float* __restrict__ bnB)
{
    int i = blockIdx.x * 256 + threadIdx.x;
    if (i < 256 * 512) { gwb[i] = f2bf(g_w[i]); wwb[i] = f2bf(W_w[i]); }
    if (i < 512) {
        float is = rsqrtf(var[i] + 1e-5f);
        float a = gamma[i] * is;
        bnA[i] = a;
        bnB[i] = (W_b[i] - mean[i]) * a + beta[i];
    }
}

// ---------------- fused Q+K build: read x once, write Q^T bf16 and pooled K^T bf16
// Block: 32 channels x 128 positions (= 2 image rows).  grid (32, 16, 8), block 256.
__global__ __launch_bounds__(256) void build_qk(
    const float* __restrict__ x, unsigned short* __restrict__ Qh,
    unsigned short* __restrict__ Kh)
{
    __shared__ float t[32][129];   // +1 pad: conflict-free transposed reads
    int b = blockIdx.z;
    int p0 = blockIdx.x * 128, c0 = blockIdx.y * 32;
    const float* xb = x + (long)b * 512 * 4096;
    int tid = threadIdx.x;
    for (int i = 0; i < 16; i++) {
        int idx = i * 256 + tid;
        int c = idx >> 7, p = idx & 127;
        t[c][p] = xb[(long)(c0 + c) * 4096 + p0 + p];
    }
    __syncthreads();
    unsigned short* qb = Qh + (long)b * 4096 * 512;
    for (int i = 0; i < 16; i++) {
        int idx = i * 256 + tid;
        int p = idx >> 5, c = idx & 31;
        qb[(long)(p0 + p) * 512 + c0 + c] = f2bf(t[c][p]);
    }
    unsigned short* kb = Kh + (long)b * 1024 * 512;
    int kp0 = p0 >> 2;   // pooled row (p0/128)*32
    for (int i = 0; i < 4; i++) {
        int idx = i * 256 + tid;
        int w = idx >> 5, c = idx & 31;
        float v = fmaxf(fmaxf(t[c][2 * w], t[c][2 * w + 1]),
                        fmaxf(t[c][64 + 2 * w], t[c][64 + 2 * w + 1]));
        kb[(long)(kp0 + w) * 512 + c0 + c] = f2bf(v);
    }
}

// ---------------- V build: Gp[b][ci][k'] = bf16(g_b[ci] + maxpool2(Gt)[ci][k'])
// Gt is bf16 [b][p=4096][ci=256].  grid (1024/32, 256/8, 8), block 256
__global__ __launch_bounds__(256) void build_v(
    const unsigned short* __restrict__ Gt, const float* __restrict__ g_b,
    unsigned short* __restrict__ Gp)
{
    int b = blockIdx.z;
    int k  = blockIdx.x * 32 + (threadIdx.x & 31);
    int ci = blockIdx.y * 8 + (threadIdx.x >> 5);
    int h = k >> 5, w = k & 31;
    const unsigned short* g = Gt + (long)b * 4096 * 256;
    long p = (long)(h * 128 + w * 2) * 256 + ci;
    float v0 = bf2f(g[p]),        v1 = bf2f(g[p + 256]);
    float v2 = bf2f(g[p + 64*256]), v3 = bf2f(g[p + 65*256]);
    float v = fmaxf(fmaxf(v0, v1), fmaxf(v2, v3)) + g_b[ci];
    Gp[(long)b * 256 * 1024 + (long)ci * 1024 + k] = f2bf(v);
}

// ------------------------------------------- fused softmax + PV (deferred norm)
// Per block: 64 q-rows, full 1024 keys, full 256 ci.
// Mrow[q][16] = per-64-col logit maxima from QK epilogue (exact f32).
// p = exp(s - m) unnormalized -> bf16 -> MFMA; row sums accumulated alongside;
// 1/l applied in epilogue.  No pass-1 S scan.
__global__ __launch_bounds__(256) void pv_fused(
    const unsigned short* __restrict__ S, long sbstr,
    const float* __restrict__ Mrow, long mbstr,
    const unsigned short* __restrict__ Gp, long gbstr,
    unsigned short* __restrict__ Y, long ybstr)
{
    __shared__ unsigned short lV[256 * 64];   // 32 KB
    __shared__ unsigned short lP[64 * 64];    // 8 KB
    __shared__ float lm[64], li[64];

    const int tid = threadIdx.x;
    const int wid = tid >> 6, lane = tid & 63;

    // XCD-aware remap: each XCD owns one batch's q-blocks (S, V stay L2-local)
    unsigned gx = gridDim.x, gy = gridDim.y;
    unsigned nwg = gx * gy;
    unsigned lin = blockIdx.x + gx * blockIdx.y;
    unsigned l = ((nwg & 7u) == 0u) ? ((lin & 7u) * (nwg >> 3) + (lin >> 3)) : lin;
    unsigned bx = l % gx, by = l / gx;

    const int q0 = (int)bx * 64;
    const unsigned short* Sb = S + by * sbstr + (long)q0 * 1024;
    const unsigned short* Gb = Gp + by * gbstr;
    unsigned short* Yb = Y + by * ybstr + (long)q0 * 256;

    // row max from Mrow tiles (exact, f32)
    if (tid < 64) {
        const float* mr = Mrow + by * mbstr + (long)(q0 + tid) * 16;
        float m = mr[0];
        for (int j = 1; j < 16; j++) m = fmaxf(m, mr[j]);
        lm[tid] = m;
    }

    const int wr = wid >> 1, wc = wid & 1;
    const int lr = lane & 15, lg = lane >> 4;
    const int srA = lane >> 3;
    const int scg = (((lane & 7) ^ srA) << 3);
    const int pr = tid >> 2;            // lP row 0..63
    const int pc = (tid & 3) * 2;       // chunk base (2 chunks of 8 keys)

    f32x4 acc[2][8];
    for (int mi = 0; mi < 2; mi++)
        for (int ni = 0; ni < 8; ni++)
            acc[mi][ni] = (f32x4){0.f, 0.f, 0.f, 0.f};
    float psum = 0.f;                   // this thread's quarter-row sum of p

    for (int kb = 0; kb < 16; kb++) {
        __syncthreads();   // prev MFMA reads done; lm visible at kb=0
        // stage V tile [256 ci][64 keys] (linear LDS dest, pre-swizzled source)
        for (int i = 0; i < 8; i++) {
            int cibase = i * 32 + wid * 8;
            gll16(Gb + (long)(cibase + srA) * 1024 + kb * 64 + scg, &lV[cibase * 64]);
        }
        // P chunk: p = exp(s - m) -> bf16 -> lP (XOR chunk swizzle); overlaps DMA
        {
            float m = lm[pr];
            const unsigned short* sp = Sb + (long)pr * 1024 + kb * 64 + pc * 8;
            for (int j = 0; j < 2; j++) {
                ushort8_t v = *(const ushort8_t*)(sp + j * 8);
                ushort8_t o8;
                for (int e = 0; e < 8; e++) {
                    float pe = __expf(bf2f(v[e]) - m);
                    psum += pe;
                    o8[e] = f2bf(pe);
                }
                int c = pc + j;
                *(ushort8_t*)(&lP[pr * 64 + ((c ^ (pr & 7)) * 8)]) = o8;
            }
        }
        __syncthreads();   // drains vmcnt(0) + LDS writes
        for (int ks = 0; ks < 2; ks++) {
            short8_t af[2], bfr[8];
            for (int mi = 0; mi < 2; mi++) {
                int row = wr * 32 + mi * 16 + lr;
                int ch = ((ks * 4 + lg) ^ (row & 7)) * 8;
                af[mi] = *(const short8_t*)(&lP[row * 64 + ch]);
            }
            for (int ni = 0; ni < 8; ni++) {
                int row = wc * 128 + ni * 16 + lr;
                int ch = ((ks * 4 + lg) ^ (row & 7)) * 8;
                bfr[ni] = *(const short8_t*)(&lV[row * 64 + ch]);
            }
            for (int mi = 0; mi < 2; mi++)
                for (int ni = 0; ni < 8; ni++)
                    acc[mi][ni] = __builtin_amdgcn_mfma_f32_16x16x32_bf16(
                        af[mi], bfr[ni], acc[mi][ni], 0, 0, 0);
        }
    }

    // reduce 4 partial sums per row -> li
    psum += __shfl_xor(psum, 1);
    psum += __shfl_xor(psum, 2);
    if ((tid & 3) == 0) li[pr] = 1.0f / psum;
    __syncthreads();

    // epilogue: Y[row][ci] = bf16(acc * 1/l)
    for (int mi = 0; mi < 2; mi++) {
        for (int ni = 0; ni < 8; ni++) {
            int ci = wc * 128 + ni * 16 + lr;
            int rbase = wr * 32 + mi * 16 + lg * 4;
            for (int r = 0; r < 4; r++) {
                int row = rbase + r;
                Yb[(long)row * 256 + ci] = f2bf(acc[mi][ni][r] * li[row]);
            }
        }
    }
}

// -------------------------------------------------------------------- GEMM
// C[m][n] = sum_k A[m][k]*B[n][k].  128x128 tile, BK=64, 4 waves 2x2.
// global_load_lds staging (linear LDS dest, XOR-swizzled source; read same XOR).
// XCD block remap when nwg%8==0.
// EPI: 0 f32 store, 1 bf16 store, 2 v*bnA[m]+bnB[m]+Xres f32 store.
// ROWMAX: also write per-row max of this block's 2 wave-col tiles to
//         Mrow[z*mbstr + row*16 + bx*2+wc] (f32).
template<int EPI, int ROWMAX>
__global__ __launch_bounds__(256) void gemm_abt(
    const unsigned short* __restrict__ A, int lda, long abstr,
    const unsigned short* __restrict__ B, int ldb, long bbstr,
    void* __restrict__ Cv, int ldc, long cbstr,
    int K,
    const float* __restrict__ bnA, const float* __restrict__ bnB,
    const float* __restrict__ Xres, long xbstr,
    float* __restrict__ Mrow, long mbstr)
{
    __shared__ unsigned short lA[128 * 64];
    __shared__ unsigned short lB[128 * 64];
    const int tid = threadIdx.x;
    const int wid = tid >> 6, lane = tid & 63;

    // ---- XCD-aware block remap (bijective; identity if nwg%8 != 0)
    unsigned gx = gridDim.x, gy = gridDim.y;
    unsigned nwg = gx * gy * gridDim.z;
    unsigned lin = blockIdx.x + gx * (blockIdx.y + gy * blockIdx.z);
    unsigned l = ((nwg & 7u) == 0u) ? ((lin & 7u) * (nwg >> 3) + (lin >> 3)) : lin;
    unsigned bx = l % gx;
    unsigned rem = l / gx;
    unsigned by = rem % gy;
    unsigned bz = rem / gy;

    const int z = (int)bz;
    const int m0 = (int)by * 128, n0 = (int)bx * 128;
    const unsigned short* Ab = A + z * abstr;
    const unsigned short* Bb = B + z * bbstr;
    const int wr = wid >> 1, wc = wid & 1;
    const int lr = lane & 15, lg = lane >> 4;

    const int srA = lane >> 3;                         // 0..7
    const int scg = (((lane & 7) ^ srA) << 3);         // element offset 0..56

    f32x4 acc[4][4];
    for (int mi = 0; mi < 4; mi++)
        for (int ni = 0; ni < 4; ni++)
            acc[mi][ni] = (f32x4){0.f, 0.f, 0.f, 0.f};

    for (int k0 = 0; k0 < K; k0 += 64) {
        __syncthreads();   // previous iter's LDS reads complete
        for (int i = 0; i < 4; i++) {
            int rowbase = i * 32 + wid * 8;
            gll16(Ab + (long)(m0 + rowbase + srA) * lda + k0 + scg, &lA[rowbase * 64]);
            gll16(Bb + (long)(n0 + rowbase + srA) * ldb + k0 + scg, &lB[rowbase * 64]);
        }
        __syncthreads();   // drains vmcnt(0): tiles resident
        for (int kk = 0; kk < 2; kk++) {
            short8_t af[4], bfr[4];
            for (int mi = 0; mi < 4; mi++) {
                int row = wr * 64 + mi * 16 + lr;
                int ch = ((kk * 4 + lg) ^ (row & 7)) * 8;
                af[mi] = *(const short8_t*)(&lA[row * 64 + ch]);
            }
            for (int ni = 0; ni < 4; ni++) {
                int row = wc * 64 + ni * 16 + lr;
                int ch = ((kk * 4 + lg) ^ (row & 7)) * 8;
                bfr[ni] = *(const short8_t*)(&lB[row * 64 + ch]);
            }
            for (int mi = 0; mi < 4; mi++)
                for (int ni = 0; ni < 4; ni++)
                    acc[mi][ni] = __builtin_amdgcn_mfma_f32_16x16x32_bf16(
                        af[mi], bfr[ni], acc[mi][ni], 0, 0, 0);
        }
    }

    if (ROWMAX) {
        // per-row max over this block's 64-col wave tile; 16 lanes share a row-set
        for (int mi = 0; mi < 4; mi++) {
            for (int r = 0; r < 4; r++) {
                float mx = fmaxf(fmaxf(acc[mi][0][r], acc[mi][1][r]),
                                 fmaxf(acc[mi][2][r], acc[mi][3][r]));
                mx = fmaxf(mx, __shfl_xor(mx, 1));
                mx = fmaxf(mx, __shfl_xor(mx, 2));
                mx = fmaxf(mx, __shfl_xor(mx, 4));
                mx = fmaxf(mx, __shfl_xor(mx, 8));
                if (lr == 0) {
                    int row = m0 + wr * 64 + mi * 16 + lg * 4 + r;
                    Mrow[z * mbstr + (long)row * 16 + bx * 2 + wc] = mx;
                }
            }
        }
    }

    // epilogue: lane holds D[row=(lane>>4)*4+r][col=lane&15]
    for (int mi = 0; mi < 4; mi++) {
        for (int ni = 0; ni < 4; ni++) {
            int ncol = n0 + wc * 64 + ni * 16 + lr;
            int mrow = m0 + wr * 64 + mi * 16 + lg * 4;
            for (int r = 0; r < 4; r++) {
                int row = mrow + r;
                float v = acc[mi][ni][r];
                long idx = z * cbstr + (long)row * ldc + ncol;
                if (EPI == 0) {
                    ((float*)Cv)[idx] = v;
                } else if (EPI == 1) {
                    ((unsigned short*)Cv)[idx] = f2bf(v);
                } else {
                    float o = v * bnA[row] + bnB[row] + Xres[z * xbstr + (long)row * ldc + ncol];
                    ((float*)Cv)[idx] = o;
                }
            }
        }
    }
}

// fallback if workspace too small (diagnostic: out = x)
__global__ void copy_residual(const float* __restrict__ x, float* __restrict__ out, long n)
{
    for (long i = blockIdx.x * 256ll + threadIdx.x; i < n; i += (long)gridDim.x * 256)
        out[i] = x[i];
}

extern "C" void kernel_launch(void* const* d_in, const int* in_sizes, int n_in,
                              void* d_out, int out_size, void* d_ws, size_t ws_size,
                              hipStream_t stream)
{
    const float* x     = (const float*)d_in[0];
    const float* g_w   = (const float*)d_in[1];
    const float* g_b   = (const float*)d_in[2];
    const float* W_w   = (const float*)d_in[3];
    const float* W_b   = (const float*)d_in[4];
    const float* gamma = (const float*)d_in[5];
    const float* beta  = (const float*)d_in[6];
    const float* mean  = (const float*)d_in[7];
    const float* var   = (const float*)d_in[8];
    float* out = (float*)d_out;

    char* ws = (char*)d_ws;
    size_t o = 0;
    auto alloc = [&](size_t bytes) { size_t r = o; o = (o + bytes + 255) & ~(size_t)255; return r; };
    size_t o_gwb = alloc(256 * 512 * 2);
    size_t o_wwb = alloc(512 * 256 * 2);
    size_t o_bnA = alloc(512 * 4);
    size_t o_bnB = alloc(512 * 4);
    size_t o_q   = alloc(8ull * 4096 * 512 * 2);   // Qh bf16
    size_t o_k   = alloc(8ull * 1024 * 512 * 2);   // Kh bf16
    size_t o_gp  = alloc(8ull * 256 * 1024 * 2);   // V^T (pooled g, bf16)
    size_t o_y   = alloc(8ull * 4096 * 256 * 2);   // Y (also holds Gt before pooling)
    size_t o_m   = alloc(8ull * 4096 * 16 * 4);    // Mrow f32 (QK row-tile maxima)
    size_t o_s   = o;                               // S bf16 logits
    const size_t srow_bytes = 1024ull * 2;          // one S row (bf16)
    const size_t sb1 = 4096ull * srow_bytes;        // one batch of S (8 MB)

    // Plan: G = batches of S at once (z-grouped); else RC = row-chunk within a batch.
    int G = 0, RC = 0;
    if      (o_s + 8 * sb1 <= ws_size) G = 8;
    else if (o_s + 4 * sb1 <= ws_size) G = 4;
    else if (o_s + 2 * sb1 <= ws_size) G = 2;
    else if (o_s + 1 * sb1 <= ws_size) G = 1;
    else {
        for (int rc = 2048; rc >= 128; rc >>= 1)
            if (o_s + (size_t)rc * srow_bytes <= ws_size) { RC = rc; break; }
        if (!RC) {  // ws too small — diagnostic fallback
            copy_residual<<<dim3(2048), dim3(256), 0, stream>>>(x, out, (long)out_size);
            return;
        }
    }

    unsigned short* gwb = (unsigned short*)(ws + o_gwb);
    unsigned short* wwb = (unsigned short*)(ws + o_wwb);
    float* bnA = (float*)(ws + o_bnA);
    float* bnB = (float*)(ws + o_bnB);
    unsigned short* Qh  = (unsigned short*)(ws + o_q);
    unsigned short* Kh  = (unsigned short*)(ws + o_k);
    unsigned short* Gp  = (unsigned short*)(ws + o_gp);
    unsigned short* Y   = (unsigned short*)(ws + o_y);
    float* Mrow         = (float*)(ws + o_m);
    unsigned short* S   = (unsigned short*)(ws + o_s);

    prep_w<<<dim3(512), dim3(256), 0, stream>>>(g_w, W_w, W_b, gamma, beta, mean, var,
                                                gwb, wwb, bnA, bnB);
    build_qk<<<dim3(32, 16, 8), dim3(256), 0, stream>>>(x, Qh, Kh);

    // G-conv: Gt[b][p][ci] (bf16, into Y slot) = Qh · gwb^T   (M=4096,N=256,K=512)
    gemm_abt<1, 0><<<dim3(2, 32, 8), dim3(256), 0, stream>>>(
        Qh, 512, 4096l * 512,
        gwb, 512, 0,
        (void*)Y, 256, 4096l * 256, 512,
        nullptr, nullptr, nullptr, 0, nullptr, 0);

    build_v<<<dim3(32, 32, 8), dim3(256), 0, stream>>>(Y, g_b, Gp);

    if (G) {
        for (int bg = 0; bg < 8; bg += G) {
            // QK^T: bf16 logits + per-row-tile maxima (K=512)
            gemm_abt<1, 1><<<dim3(8, 32, G), dim3(256), 0, stream>>>(
                Qh + (size_t)bg * 4096 * 512, 512, 4096l * 512,
                Kh + (size_t)bg * 1024 * 512, 512, 1024l * 512,
                (void*)S, 1024, 4096l * 1024, 512,
                nullptr, nullptr, nullptr, 0,
                Mrow + (size_t)bg * 4096 * 16, 4096l * 16);
            // fused softmax + PV (deferred normalization)
            pv_fused<<<dim3(64, G), dim3(256), 0, stream>>>(
                S, 4096l * 1024,
                Mrow + (size_t)bg * 4096 * 16, 4096l * 16,
                Gp + (size_t)bg * 256 * 1024, 256l * 1024,
                Y + (size_t)bg * 4096 * 256, 4096l * 256);
        }
    } else {
        // Row-chunked path (small workspace): S holds RC rows at a time.
        for (int b = 0; b < 8; b++) {
            for (int r0 = 0; r0 < 4096; r0 += RC) {
                const unsigned short* Aq = Qh + (size_t)b * 4096 * 512 + (size_t)r0 * 512;
                gemm_abt<1, 1><<<dim3(8, RC / 128, 1), dim3(256), 0, stream>>>(
                    Aq, 512, 0,
                    Kh + (size_t)b * 1024 * 512, 512, 0,
                    (void*)S, 1024, 0, 512,
                    nullptr, nullptr, nullptr, 0,
                    Mrow, 0);
                pv_fused<<<dim3(RC / 64, 1), dim3(256), 0, stream>>>(
                    S, 0,
                    Mrow, 0,
                    Gp + (size_t)b * 256 * 1024, 0,
                    Y + ((size_t)b * 4096 + r0) * 256, 0);
            }
        }
    }

    // W-conv + BN + residual: out[b][o][p] = (wwb·Y^T)*bnA[o]+bnB[o]+x  (M=512,N=4096,K=256)
    gemm_abt<2, 0><<<dim3(32, 4, 8), dim3(256), 0, stream>>>(
        wwb, 256, 0,
        Y, 256, 4096l * 256,
        (void*)out, 4096, 512l * 4096, 256,
        bnA, bnB, x, 512l * 4096,
        nullptr, 0);
}

// Round 9
// 180.084 us; speedup vs baseline: 1.8799x; 1.0162x over previous
//
#include <hip/hip_runtime.h>
#include <stdint.h>

typedef __attribute__((ext_vector_type(4))) float f32x4;
typedef __attribute__((ext_vector_type(8))) short short8_t;     // 8 bf16 for MFMA operand
typedef __attribute__((ext_vector_type(8))) unsigned short ushort8_t;

__device__ __forceinline__ unsigned short f2bf(float f) {
    unsigned int u = __builtin_bit_cast(unsigned int, f);
    u = (u + 0x7fffu + ((u >> 16) & 1u)) >> 16;   // round-to-nearest-even
    return (unsigned short)u;
}
__device__ __forceinline__ float bf2f(unsigned short h) {
    unsigned int u = ((unsigned int)h) << 16;
    return __builtin_bit_cast(float, u);
}

// async global->LDS, 16B per lane. LDS dest = wave-uniform base + lane*16.
__device__ __forceinline__ void gll16(const unsigned short* g, unsigned short* l) {
    __builtin_amdgcn_global_load_lds(
        (const __attribute__((address_space(1))) void*)g,
        (__attribute__((address_space(3))) void*)l, 16, 0, 0);
}

// ---------------------------------------------------------------- prep weights
__global__ __launch_bounds__(256) void prep_w(
    const float* __restrict__ g_w, const float* __restrict__ W_w,
    const float* __restrict__ W_b, const float* __restrict__ gamma,
    const float* __restrict__ beta, const float* __restrict__ mean,
    const float* __restrict__ var,
    unsigned short* __restrict__ gwb, unsigned short* __restrict__ wwb,
    float* __restrict__ bnA, float* __restrict__ bnB)
{
    int i = blockIdx.x * 256 + threadIdx.x;
    if (i < 256 * 512) { gwb[i] = f2bf(g_w[i]); wwb[i] = f2bf(W_w[i]); }
    if (i < 512) {
        float is = rsqrtf(var[i] + 1e-5f);
        float a = gamma[i] * is;
        bnA[i] = a;
        bnB[i] = (W_b[i] - mean[i]) * a + beta[i];
    }
}

// ---------------- fused Q+K build: read x once, write Q^T bf16 and pooled K^T bf16
// Block: 32 channels x 128 positions (= 2 image rows).  grid (32, 16, 8), block 256.
__global__ __launch_bounds__(256) void build_qk(
    const float* __restrict__ x, unsigned short* __restrict__ Qh,
    unsigned short* __restrict__ Kh)
{
    __shared__ float t[32][129];   // +1 pad: conflict-free transposed reads
    int b = blockIdx.z;
    int p0 = blockIdx.x * 128, c0 = blockIdx.y * 32;
    const float* xb = x + (long)b * 512 * 4096;
    int tid = threadIdx.x;
    for (int i = 0; i < 16; i++) {
        int idx = i * 256 + tid;
        int c = idx >> 7, p = idx & 127;
        t[c][p] = xb[(long)(c0 + c) * 4096 + p0 + p];
    }
    __syncthreads();
    unsigned short* qb = Qh + (long)b * 4096 * 512;
    for (int i = 0; i < 16; i++) {
        int idx = i * 256 + tid;
        int p = idx >> 5, c = idx & 31;
        qb[(long)(p0 + p) * 512 + c0 + c] = f2bf(t[c][p]);
    }
    unsigned short* kb = Kh + (long)b * 1024 * 512;
    int kp0 = p0 >> 2;   // pooled row (p0/128)*32
    for (int i = 0; i < 4; i++) {
        int idx = i * 256 + tid;
        int w = idx >> 5, c = idx & 31;
        float v = fmaxf(fmaxf(t[c][2 * w], t[c][2 * w + 1]),
                        fmaxf(t[c][64 + 2 * w], t[c][64 + 2 * w + 1]));
        kb[(long)(kp0 + w) * 512 + c0 + c] = f2bf(v);
    }
}

// ---------------- V build: Gp[b][ci][k'] = bf16(g_b[ci] + maxpool2(Gt)[ci][k'])
// Gt is bf16 [b][p=4096][ci=256].  grid (1024/32, 256/8, 8), block 256
__global__ __launch_bounds__(256) void build_v(
    const unsigned short* __restrict__ Gt, const float* __restrict__ g_b,
    unsigned short* __restrict__ Gp)
{
    int b = blockIdx.z;
    int k  = blockIdx.x * 32 + (threadIdx.x & 31);
    int ci = blockIdx.y * 8 + (threadIdx.x >> 5);
    int h = k >> 5, w = k & 31;
    const unsigned short* g = Gt + (long)b * 4096 * 256;
    long p = (long)(h * 128 + w * 2) * 256 + ci;
    float v0 = bf2f(g[p]),        v1 = bf2f(g[p + 256]);
    float v2 = bf2f(g[p + 64*256]), v3 = bf2f(g[p + 65*256]);
    float v = fmaxf(fmaxf(v0, v1), fmaxf(v2, v3)) + g_b[ci];
    Gp[(long)b * 256 * 1024 + (long)ci * 1024 + k] = f2bf(v);
}

// ------------------------------------------- fused softmax + PV (deferred norm)
// Per block: 64 q-rows, full 1024 keys, full 256 ci.
// Pass 1: max-only scan of S (bf16, L2/L3-hot) -> lm.  No exp, no rescale chain.
// Pass 2: per 64-key block, p = exp(s-m) unnormalized -> bf16 -> MFMA;
// row sums accumulated alongside; 1/l applied in epilogue.
__global__ __launch_bounds__(256) void pv_fused(
    const unsigned short* __restrict__ S, long sbstr,
    const unsigned short* __restrict__ Gp, long gbstr,
    unsigned short* __restrict__ Y, long ybstr)
{
    __shared__ unsigned short lV[256 * 64];   // 32 KB
    __shared__ unsigned short lP[64 * 64];    // 8 KB
    __shared__ float pm[256];
    __shared__ float lm[64], li[64];

    const int tid = threadIdx.x;
    const int wid = tid >> 6, lane = tid & 63;

    // XCD-aware remap: each XCD owns one batch's q-blocks (S, V stay L2-local)
    unsigned gx = gridDim.x, gy = gridDim.y;
    unsigned nwg = gx * gy;
    unsigned lin = blockIdx.x + gx * blockIdx.y;
    unsigned l = ((nwg & 7u) == 0u) ? ((lin & 7u) * (nwg >> 3) + (lin >> 3)) : lin;
    unsigned bx = l % gx, by = l / gx;

    const int q0 = (int)bx * 64;
    const unsigned short* Sb = S + by * sbstr + (long)q0 * 1024;
    const unsigned short* Gb = Gp + by * gbstr;
    unsigned short* Yb = Y + by * ybstr + (long)q0 * 256;

    // ---- pass 1: per-row max over 1024 keys (4 threads/row, max-only)
    {
        int r = tid >> 2, qq = tid & 3;
        const unsigned short* p = Sb + (long)r * 1024 + qq * 256;
        float m = -3.0e38f;
        for (int i = 0; i < 32; i++) {
            ushort8_t v = *(const ushort8_t*)(p + i * 8);
            float c0 = fmaxf(bf2f(v[0]), bf2f(v[1]));
            float c1 = fmaxf(bf2f(v[2]), bf2f(v[3]));
            float c2 = fmaxf(bf2f(v[4]), bf2f(v[5]));
            float c3 = fmaxf(bf2f(v[6]), bf2f(v[7]));
            m = fmaxf(m, fmaxf(fmaxf(c0, c1), fmaxf(c2, c3)));
        }
        pm[tid] = m;
    }
    __syncthreads();
    if (tid < 64) {
        lm[tid] = fmaxf(fmaxf(pm[tid*4], pm[tid*4+1]),
                        fmaxf(pm[tid*4+2], pm[tid*4+3]));
    }

    const int wr = wid >> 1, wc = wid & 1;
    const int lr = lane & 15, lg = lane >> 4;
    const int srA = lane >> 3;
    const int scg = (((lane & 7) ^ srA) << 3);
    const int pr = tid >> 2;            // lP row 0..63
    const int pc = (tid & 3) * 2;       // chunk base (2 chunks of 8 keys)

    f32x4 acc[2][8];
    for (int mi = 0; mi < 2; mi++)
        for (int ni = 0; ni < 8; ni++)
            acc[mi][ni] = (f32x4){0.f, 0.f, 0.f, 0.f};
    float psum = 0.f;                   // this thread's quarter-row sum of p

    for (int kb = 0; kb < 16; kb++) {
        __syncthreads();   // prev MFMA reads done; lm visible at kb=0
        // stage V tile [256 ci][64 keys] (linear LDS dest, pre-swizzled source)
        for (int i = 0; i < 8; i++) {
            int cibase = i * 32 + wid * 8;
            gll16(Gb + (long)(cibase + srA) * 1024 + kb * 64 + scg, &lV[cibase * 64]);
        }
        // P chunk: p = exp(s - m) -> bf16 -> lP (XOR chunk swizzle); overlaps DMA
        {
            float m = lm[pr];
            const unsigned short* sp = Sb + (long)pr * 1024 + kb * 64 + pc * 8;
            for (int j = 0; j < 2; j++) {
                ushort8_t v = *(const ushort8_t*)(sp + j * 8);
                ushort8_t o8;
                for (int e = 0; e < 8; e++) {
                    float pe = __expf(bf2f(v[e]) - m);
                    psum += pe;
                    o8[e] = f2bf(pe);
                }
                int c = pc + j;
                *(ushort8_t*)(&lP[pr * 64 + ((c ^ (pr & 7)) * 8)]) = o8;
            }
        }
        __syncthreads();   // drains vmcnt(0) + LDS writes
        for (int ks = 0; ks < 2; ks++) {
            short8_t af[2], bfr[8];
            for (int mi = 0; mi < 2; mi++) {
                int row = wr * 32 + mi * 16 + lr;
                int ch = ((ks * 4 + lg) ^ (row & 7)) * 8;
                af[mi] = *(const short8_t*)(&lP[row * 64 + ch]);
            }
            for (int ni = 0; ni < 8; ni++) {
                int row = wc * 128 + ni * 16 + lr;
                int ch = ((ks * 4 + lg) ^ (row & 7)) * 8;
                bfr[ni] = *(const short8_t*)(&lV[row * 64 + ch]);
            }
            for (int mi = 0; mi < 2; mi++)
                for (int ni = 0; ni < 8; ni++)
                    acc[mi][ni] = __builtin_amdgcn_mfma_f32_16x16x32_bf16(
                        af[mi], bfr[ni], acc[mi][ni], 0, 0, 0);
        }
    }

    // reduce 4 partial sums per row -> li
    psum += __shfl_xor(psum, 1);
    psum += __shfl_xor(psum, 2);
    if ((tid & 3) == 0) li[pr] = 1.0f / psum;
    __syncthreads();

    // epilogue: Y[row][ci] = bf16(acc * 1/l)
    for (int mi = 0; mi < 2; mi++) {
        for (int ni = 0; ni < 8; ni++) {
            int ci = wc * 128 + ni * 16 + lr;
            int rbase = wr * 32 + mi * 16 + lg * 4;
            for (int r = 0; r < 4; r++) {
                int row = rbase + r;
                Yb[(long)row * 256 + ci] = f2bf(acc[mi][ni][r] * li[row]);
            }
        }
    }
}

// -------------------------------------------------------------------- GEMM
// C[m][n] = sum_k A[m][k]*B[n][k].  128x128 tile, BK=64, 4 waves 2x2.
// global_load_lds staging (linear LDS dest, XOR-swizzled source; read same XOR).
// XCD block remap when nwg%8==0.
// EPI: 0 f32 store, 1 bf16 store, 2 v*bnA[m]+bnB[m]+Xres f32 store.
template<int EPI>
__global__ __launch_bounds__(256) void gemm_abt(
    const unsigned short* __restrict__ A, int lda, long abstr,
    const unsigned short* __restrict__ B, int ldb, long bbstr,
    void* __restrict__ Cv, int ldc, long cbstr,
    int K,
    const float* __restrict__ bnA, const float* __restrict__ bnB,
    const float* __restrict__ Xres, long xbstr)
{
    __shared__ unsigned short lA[128 * 64];
    __shared__ unsigned short lB[128 * 64];
    const int tid = threadIdx.x;
    const int wid = tid >> 6, lane = tid & 63;

    // ---- XCD-aware block remap (bijective; identity if nwg%8 != 0)
    unsigned gx = gridDim.x, gy = gridDim.y;
    unsigned nwg = gx * gy * gridDim.z;
    unsigned lin = blockIdx.x + gx * (blockIdx.y + gy * blockIdx.z);
    unsigned l = ((nwg & 7u) == 0u) ? ((lin & 7u) * (nwg >> 3) + (lin >> 3)) : lin;
    unsigned bx = l % gx;
    unsigned rem = l / gx;
    unsigned by = rem % gy;
    unsigned bz = rem / gy;

    const int z = (int)bz;
    const int m0 = (int)by * 128, n0 = (int)bx * 128;
    const unsigned short* Ab = A + z * abstr;
    const unsigned short* Bb = B + z * bbstr;
    const int wr = wid >> 1, wc = wid & 1;
    const int lr = lane & 15, lg = lane >> 4;

    const int srA = lane >> 3;                         // 0..7
    const int scg = (((lane & 7) ^ srA) << 3);         // element offset 0..56

    f32x4 acc[4][4];
    for (int mi = 0; mi < 4; mi++)
        for (int ni = 0; ni < 4; ni++)
            acc[mi][ni] = (f32x4){0.f, 0.f, 0.f, 0.f};

    for (int k0 = 0; k0 < K; k0 += 64) {
        __syncthreads();   // previous iter's LDS reads complete
        for (int i = 0; i < 4; i++) {
            int rowbase = i * 32 + wid * 8;
            gll16(Ab + (long)(m0 + rowbase + srA) * lda + k0 + scg, &lA[rowbase * 64]);
            gll16(Bb + (long)(n0 + rowbase + srA) * ldb + k0 + scg, &lB[rowbase * 64]);
        }
        __syncthreads();   // drains vmcnt(0): tiles resident
        for (int kk = 0; kk < 2; kk++) {
            short8_t af[4], bfr[4];
            for (int mi = 0; mi < 4; mi++) {
                int row = wr * 64 + mi * 16 + lr;
                int ch = ((kk * 4 + lg) ^ (row & 7)) * 8;
                af[mi] = *(const short8_t*)(&lA[row * 64 + ch]);
            }
            for (int ni = 0; ni < 4; ni++) {
                int row = wc * 64 + ni * 16 + lr;
                int ch = ((kk * 4 + lg) ^ (row & 7)) * 8;
                bfr[ni] = *(const short8_t*)(&lB[row * 64 + ch]);
            }
            for (int mi = 0; mi < 4; mi++)
                for (int ni = 0; ni < 4; ni++)
                    acc[mi][ni] = __builtin_amdgcn_mfma_f32_16x16x32_bf16(
                        af[mi], bfr[ni], acc[mi][ni], 0, 0, 0);
        }
    }

    // epilogue: lane holds D[row=(lane>>4)*4+r][col=lane&15]
    for (int mi = 0; mi < 4; mi++) {
        for (int ni = 0; ni < 4; ni++) {
            int ncol = n0 + wc * 64 + ni * 16 + lr;
            int mrow = m0 + wr * 64 + mi * 16 + lg * 4;
            for (int r = 0; r < 4; r++) {
                int row = mrow + r;
                float v = acc[mi][ni][r];
                long idx = z * cbstr + (long)row * ldc + ncol;
                if (EPI == 0) {
                    ((float*)Cv)[idx] = v;
                } else if (EPI == 1) {
                    ((unsigned short*)Cv)[idx] = f2bf(v);
                } else {
                    float o = v * bnA[row] + bnB[row] + Xres[z * xbstr + (long)row * ldc + ncol];
                    ((float*)Cv)[idx] = o;
                }
            }
        }
    }
}

// fallback if workspace too small (diagnostic: out = x)
__global__ void copy_residual(const float* __restrict__ x, float* __restrict__ out, long n)
{
    for (long i = blockIdx.x * 256ll + threadIdx.x; i < n; i += (long)gridDim.x * 256)
        out[i] = x[i];
}

extern "C" void kernel_launch(void* const* d_in, const int* in_sizes, int n_in,
                              void* d_out, int out_size, void* d_ws, size_t ws_size,
                              hipStream_t stream)
{
    const float* x     = (const float*)d_in[0];
    const float* g_w   = (const float*)d_in[1];
    const float* g_b   = (const float*)d_in[2];
    const float* W_w   = (const float*)d_in[3];
    const float* W_b   = (const float*)d_in[4];
    const float* gamma = (const float*)d_in[5];
    const float* beta  = (const float*)d_in[6];
    const float* mean  = (const float*)d_in[7];
    const float* var   = (const float*)d_in[8];
    float* out = (float*)d_out;

    char* ws = (char*)d_ws;
    size_t o = 0;
    auto alloc = [&](size_t bytes) { size_t r = o; o = (o + bytes + 255) & ~(size_t)255; return r; };
    size_t o_gwb = alloc(256 * 512 * 2);
    size_t o_wwb = alloc(512 * 256 * 2);
    size_t o_bnA = alloc(512 * 4);
    size_t o_bnB = alloc(512 * 4);
    size_t o_q   = alloc(8ull * 4096 * 512 * 2);   // Qh bf16
    size_t o_k   = alloc(8ull * 1024 * 512 * 2);   // Kh bf16
    size_t o_gp  = alloc(8ull * 256 * 1024 * 2);   // V^T (pooled g, bf16)
    size_t o_y   = alloc(8ull * 4096 * 256 * 2);   // Y (also holds Gt before pooling)
    size_t o_s   = o;                               // S bf16 logits
    const size_t srow_bytes = 1024ull * 2;          // one S row (bf16)
    const size_t sb1 = 4096ull * srow_bytes;        // one batch of S (8 MB)

    // Plan: G = batches of S at once (z-grouped); else RC = row-chunk within a batch.
    int G = 0, RC = 0;
    if      (o_s + 8 * sb1 <= ws_size) G = 8;
    else if (o_s + 4 * sb1 <= ws_size) G = 4;
    else if (o_s + 2 * sb1 <= ws_size) G = 2;
    else if (o_s + 1 * sb1 <= ws_size) G = 1;
    else {
        for (int rc = 2048; rc >= 128; rc >>= 1)
            if (o_s + (size_t)rc * srow_bytes <= ws_size) { RC = rc; break; }
        if (!RC) {  // ws too small — diagnostic fallback
            copy_residual<<<dim3(2048), dim3(256), 0, stream>>>(x, out, (long)out_size);
            return;
        }
    }

    unsigned short* gwb = (unsigned short*)(ws + o_gwb);
    unsigned short* wwb = (unsigned short*)(ws + o_wwb);
    float* bnA = (float*)(ws + o_bnA);
    float* bnB = (float*)(ws + o_bnB);
    unsigned short* Qh  = (unsigned short*)(ws + o_q);
    unsigned short* Kh  = (unsigned short*)(ws + o_k);
    unsigned short* Gp  = (unsigned short*)(ws + o_gp);
    unsigned short* Y   = (unsigned short*)(ws + o_y);
    unsigned short* S   = (unsigned short*)(ws + o_s);

    prep_w<<<dim3(512), dim3(256), 0, stream>>>(g_w, W_w, W_b, gamma, beta, mean, var,
                                                gwb, wwb, bnA, bnB);
    build_qk<<<dim3(32, 16, 8), dim3(256), 0, stream>>>(x, Qh, Kh);

    // G-conv: Gt[b][p][ci] (bf16, into Y slot) = Qh · gwb^T   (M=4096,N=256,K=512)
    gemm_abt<1><<<dim3(2, 32, 8), dim3(256), 0, stream>>>(
        Qh, 512, 4096l * 512,
        gwb, 512, 0,
        (void*)Y, 256, 4096l * 256, 512,
        nullptr, nullptr, nullptr, 0);

    build_v<<<dim3(32, 32, 8), dim3(256), 0, stream>>>(Y, g_b, Gp);

    if (G) {
        for (int bg = 0; bg < 8; bg += G) {
            // QK^T: bf16 in, bf16 logits out (K=512)
            gemm_abt<1><<<dim3(8, 32, G), dim3(256), 0, stream>>>(
                Qh + (size_t)bg * 4096 * 512, 512, 4096l * 512,
                Kh + (size_t)bg * 1024 * 512, 512, 1024l * 512,
                (void*)S, 1024, 4096l * 1024, 512,
                nullptr, nullptr, nullptr, 0);
            // fused softmax + PV (max pre-pass + deferred normalization)
            pv_fused<<<dim3(64, G), dim3(256), 0, stream>>>(
                S, 4096l * 1024,
                Gp + (size_t)bg * 256 * 1024, 256l * 1024,
                Y + (size_t)bg * 4096 * 256, 4096l * 256);
        }
    } else {
        // Row-chunked path (small workspace): S holds RC rows at a time.
        for (int b = 0; b < 8; b++) {
            for (int r0 = 0; r0 < 4096; r0 += RC) {
                const unsigned short* Aq = Qh + (size_t)b * 4096 * 512 + (size_t)r0 * 512;
                gemm_abt<1><<<dim3(8, RC / 128, 1), dim3(256), 0, stream>>>(
                    Aq, 512, 0,
                    Kh + (size_t)b * 1024 * 512, 512, 0,
                    (void*)S, 1024, 0, 512,
                    nullptr, nullptr, nullptr, 0);
                pv_fused<<<dim3(RC / 64, 1), dim3(256), 0, stream>>>(
                    S, 0,
                    Gp + (size_t)b * 256 * 1024, 0,
                    Y + ((size_t)b * 4096 + r0) * 256, 0);
            }
        }
    }

    // W-conv + BN + residual: out[b][o][p] = (wwb·Y^T)*bnA[o]+bnB[o]+x  (M=512,N=4096,K=256)
    gemm_abt<2><<<dim3(32, 4, 8), dim3(256), 0, stream>>>(
        wwb, 256, 0,
        Y, 256, 4096l * 256,
        (void*)out, 4096, 512l * 4096, 256,
        bnA, bnB, x, 512l * 4096);
}